// Round 10
// baseline (242.960 us; speedup 1.0000x reference)
//
#include <hip/hip_runtime.h>

// ---- bucket-sort CSR parameters (n <= 131072, so src/dst fit in 17 bits) ----
#define NPB_SHIFT 7
#define NPB       128      // nodes per bucket
#define CHUNK     4096     // edges per hist/scatter block (16 per thread)
#define STAGE_CAP 8192     // bucket_build LDS staging (ints); avg bucket ~4092
#define NBKT_MAX  1024     // LDS bin cap (needs nbkt <= 1024)

// ---------------- pass 1: per-block LDS histogram of dst buckets ----------------

__global__ void hist_kernel(const int* __restrict__ dst, int* __restrict__ hist,
                            int E, int HBr, int nbkt) {
    __shared__ int bins[NBKT_MAX];
    int tid = threadIdx.x;
    for (int i = tid; i < nbkt; i += 256) bins[i] = 0;
    __syncthreads();
    int start = blockIdx.x * CHUNK;
    #pragma unroll
    for (int j = 0; j < 16; ++j) {
        int e = start + j * 256 + tid;
        if (e < E) atomicAdd(&bins[dst[e] >> NPB_SHIFT], 1);
    }
    __syncthreads();
    for (int i = tid; i < nbkt; i += 256)
        hist[(size_t)i * HBr + blockIdx.x] = bins[i];
}

// ---------------- 3-phase exclusive scan over hist matrix (in place) ----------------

__global__ void scan_block8_kernel(int* data, int* __restrict__ partial, int len) {
    __shared__ int wtot[16];
    int tid = threadIdx.x, lane = tid & 63, wid = tid >> 6;
    int base = blockIdx.x * 8192 + tid * 8;
    int v[8]; int s = 0;
    #pragma unroll
    for (int j = 0; j < 8; ++j) {
        int i = base + j;
        v[j] = (i < len) ? data[i] : 0;
        s += v[j];
    }
    int inc = s;
    #pragma unroll
    for (int o = 1; o < 64; o <<= 1) { int t = __shfl_up(inc, o); if (lane >= o) inc += t; }
    if (lane == 63) wtot[wid] = inc;
    __syncthreads();
    if (tid == 0) {
        int run = 0;
        #pragma unroll
        for (int w = 0; w < 16; ++w) { int t = wtot[w]; wtot[w] = run; run += t; }
        partial[blockIdx.x] = run;
    }
    __syncthreads();
    int excl = wtot[wid] + inc - s;
    #pragma unroll
    for (int j = 0; j < 8; ++j) {
        int i = base + j;
        if (i < len) data[i] = excl;
        excl += v[j];
    }
}

__global__ void scan_partials_kernel(int* partial, int nb) {
    int t = threadIdx.x;  // 64 threads; nb <= 128
    int i0 = 2 * t, i1 = 2 * t + 1;
    int v0 = (i0 < nb) ? partial[i0] : 0;
    int v1 = (i1 < nb) ? partial[i1] : 0;
    int s = v0 + v1;
    int inc = s;
    #pragma unroll
    for (int o = 1; o < 64; o <<= 1) { int u = __shfl_up(inc, o); if (t >= o) inc += u; }
    int excl = inc - s;
    if (i0 < nb) partial[i0] = excl;
    if (i1 < nb) partial[i1] = excl + v0;
}

__global__ void add_base_kernel(int* data, const int* __restrict__ partial, int len) {
    int i = blockIdx.x * blockDim.x + threadIdx.x;
    if (i < len) data[i] += partial[i >> 13];
}

// ---------------- pass 2: tile-sort scatter into bucket-ordered ebuf ----------------
// payload packed: (dst & 127) << 17 | src   (src < 2^17)

__global__ void scatter_kernel(const int* __restrict__ src, const int* __restrict__ dst,
                               const int* __restrict__ offset, int* __restrict__ ebuf,
                               int E, int HBr, int nbkt) {
    __shared__ int gbase[NBKT_MAX];
    __shared__ int thist[NBKT_MAX];
    __shared__ int toff[NBKT_MAX + 1];
    __shared__ int stage[CHUNK];
    __shared__ unsigned short bstage[CHUNK];
    __shared__ int wtot4[4];
    int tid = threadIdx.x, lane = tid & 63, wid = tid >> 6;
    for (int i = tid; i < nbkt; i += 256) gbase[i] = offset[(size_t)i * HBr + blockIdx.x];
    for (int i = tid; i < NBKT_MAX; i += 256) thist[i] = 0;
    __syncthreads();
    int start = blockIdx.x * CHUNK;
    int s_[16], d_[16], r_[16];
    #pragma unroll
    for (int j = 0; j < 16; ++j) {
        int e = start + j * 256 + tid;
        if (e < E) {
            s_[j] = src[e];
            d_[j] = dst[e];
            r_[j] = atomicAdd(&thist[d_[j] >> NPB_SHIFT], 1);
        } else {
            d_[j] = -1;
        }
    }
    __syncthreads();
    int a0 = thist[4 * tid], a1 = thist[4 * tid + 1],
        a2 = thist[4 * tid + 2], a3 = thist[4 * tid + 3];
    int ss = a0 + a1 + a2 + a3;
    int inc = ss;
    #pragma unroll
    for (int o = 1; o < 64; o <<= 1) { int t = __shfl_up(inc, o); if (lane >= o) inc += t; }
    if (lane == 63) wtot4[wid] = inc;
    __syncthreads();
    int wbase = 0;
    for (int w = 0; w < wid; ++w) wbase += wtot4[w];
    int excl = wbase + inc - ss;
    toff[4 * tid]     = excl;
    toff[4 * tid + 1] = excl + a0;
    toff[4 * tid + 2] = excl + a0 + a1;
    toff[4 * tid + 3] = excl + a0 + a1 + a2;
    if (tid == 255) toff[1024] = excl + ss;  // total valid
    __syncthreads();
    #pragma unroll
    for (int j = 0; j < 16; ++j) {
        if (d_[j] >= 0) {
            int b = d_[j] >> NPB_SHIFT;
            int q = toff[b] + r_[j];
            stage[q]  = ((d_[j] & (NPB - 1)) << 17) | s_[j];
            bstage[q] = (unsigned short)b;
        }
    }
    __syncthreads();
    int total = toff[1024];
    for (int j = tid; j < total; j += 256) {
        int b = bstage[j];
        ebuf[gbase[b] + (j - toff[b])] = stage[j];
    }
}

// ---------------- pass 3: per-bucket CSR build + row_start + dinv ----------------

__global__ void bucket_build_kernel(const int* __restrict__ ebuf, const int* __restrict__ offset,
                                    int* __restrict__ csr_src, int* __restrict__ row_start,
                                    float* __restrict__ dinv, int E, int HBr, int nbkt, int n) {
    __shared__ int cnt[NPB], cur[NPB];
    __shared__ int stage[STAGE_CAP];
    __shared__ int wtot2[2];
    int tid = threadIdx.x;
    int k = blockIdx.x;
    int bb = offset[(size_t)k * HBr];
    int be = (k + 1 < nbkt) ? offset[(size_t)(k + 1) * HBr] : E;
    int bsize = be - bb;
    if (tid < NPB) cnt[tid] = 0;
    __syncthreads();
    for (int e = bb + tid; e < be; e += 256) atomicAdd(&cnt[ebuf[e] >> 17], 1);
    __syncthreads();
    int lane = tid & 63, wid = tid >> 6;
    int c = 0, inc = 0;
    if (tid < NPB) {
        c = cnt[tid];
        inc = c;
        #pragma unroll
        for (int o = 1; o < 64; o <<= 1) { int t = __shfl_up(inc, o); if (lane >= o) inc += t; }
        if (lane == 63) wtot2[wid] = inc;
    }
    __syncthreads();
    if (tid < NPB) {
        int base = (wid == 1) ? wtot2[0] : 0;
        int excl = base + inc - c;
        cur[tid] = excl;
        int node = k * NPB + tid;
        if (node < n) {
            row_start[node] = bb + excl;
            dinv[node] = rsqrtf((float)(c + 1));  // self-loop
        }
    }
    if (k == 0 && tid == 0) row_start[n] = E;
    __syncthreads();
    if (bsize <= STAGE_CAP) {
        for (int e = bb + tid; e < be; e += 256) {
            int v = ebuf[e];
            int r = atomicAdd(&cur[v >> 17], 1);
            stage[r] = v & 0x1FFFF;
        }
        __syncthreads();
        for (int j = tid; j < bsize; j += 256) csr_src[bb + j] = stage[j];  // coalesced
    } else {
        for (int e = bb + tid; e < be; e += 256) {
            int v = ebuf[e];
            int r = atomicAdd(&cur[v >> 17], 1);
            csr_src[bb + r] = v & 0x1FFFF;
        }
    }
}

// ---------------- pad + scale: g0[i][k] = (k<11) ? x[i][k]*dinv[i] : 0  (16-wide) ------------

__global__ void pad_scale_kernel(const float* __restrict__ x, const float* __restrict__ dinv,
                                 float* __restrict__ g, int n) {
    int i = blockIdx.x * blockDim.x + threadIdx.x;
    if (i >= n) return;
    float s = dinv[i];
    float v[16];
    #pragma unroll
    for (int k = 0; k < 11; ++k) v[k] = x[i * 11 + k] * s;
    #pragma unroll
    for (int k = 11; k < 16; ++k) v[k] = 0.f;
    #pragma unroll
    for (int k = 0; k < 16; ++k) g[i * 16 + k] = v[k];
}

// ---------------- gather-aggregate (vectorized, unfused) ----------------
// pre[d] = dinv[d] * (sum_{s in N(d)} g[s] + g[d]);  g rows carry dinv[s].
// One wave per node. 8 lanes per row (float2 for FIN=16, float4 for FIN=32);
// 8 rows per load instruction; 64 rows per batch. Index distribution via
// broadcast loads (8 lanes share each address) — no shuffles. Unmasked fast
// path for full batches; single masked batch handles the remainder with all
// 16 requests (8 idx + 8 gathers) in flight.

template <int FOUT>
__global__ void aggregate_kernel(const float* __restrict__ g,
                                 const int* __restrict__ row_start,
                                 const int* __restrict__ csr_src,
                                 const float* __restrict__ dinv,
                                 float* __restrict__ pre, int n) {
    constexpr int VW = FOUT / 8;   // floats per lane (2 or 4)
    int lane = threadIdx.x & 63;
    int wid  = threadIdx.x >> 6;
    int node = blockIdx.x * (blockDim.x >> 6) + wid;
    if (node >= n) return;
    int q   = lane & 7;        // chunk index within row
    int grp = lane >> 3;       // row slot within each 8-row group
    int beg = row_start[node];
    int end = row_start[node + 1];
    float acc[VW];
    #pragma unroll
    for (int c = 0; c < VW; ++c) acc[c] = 0.f;

    int p = beg;
    // unmasked full batches (rare for deg<64, cheap when they happen)
    for (; p + 64 <= end; p += 64) {
        int s[8];
        #pragma unroll
        for (int u = 0; u < 8; ++u) s[u] = csr_src[p + u * 8 + grp];  // broadcast x8 lanes
        if constexpr (VW == 2) {
            const float2* gv = reinterpret_cast<const float2*>(g);
            float2 v[8];
            #pragma unroll
            for (int u = 0; u < 8; ++u) v[u] = gv[(size_t)s[u] * 8 + q];
            #pragma unroll
            for (int u = 0; u < 8; ++u) { acc[0] += v[u].x; acc[1] += v[u].y; }
        } else {
            const float4* gv = reinterpret_cast<const float4*>(g);
            float4 v[8];
            #pragma unroll
            for (int u = 0; u < 8; ++u) v[u] = gv[(size_t)s[u] * 8 + q];
            #pragma unroll
            for (int u = 0; u < 8; ++u) {
                acc[0] += v[u].x; acc[1] += v[u].y; acc[2] += v[u].z; acc[3] += v[u].w;
            }
        }
    }
    // masked tail batch (the common case: deg < 64 -> single batch, 16 reqs in flight)
    if (p < end) {
        int nrem = end - p;
        int   s[8];
        float m[8];
        #pragma unroll
        for (int u = 0; u < 8; ++u) {
            int slot = u * 8 + grp;
            s[u] = csr_src[min(p + slot, end - 1)];       // clamped, in-bounds
            m[u] = (slot < nrem) ? 1.f : 0.f;
        }
        if constexpr (VW == 2) {
            const float2* gv = reinterpret_cast<const float2*>(g);
            float2 v[8];
            #pragma unroll
            for (int u = 0; u < 8; ++u) v[u] = gv[(size_t)s[u] * 8 + q];
            #pragma unroll
            for (int u = 0; u < 8; ++u) {
                acc[0] = fmaf(m[u], v[u].x, acc[0]);
                acc[1] = fmaf(m[u], v[u].y, acc[1]);
            }
        } else {
            const float4* gv = reinterpret_cast<const float4*>(g);
            float4 v[8];
            #pragma unroll
            for (int u = 0; u < 8; ++u) v[u] = gv[(size_t)s[u] * 8 + q];
            #pragma unroll
            for (int u = 0; u < 8; ++u) {
                acc[0] = fmaf(m[u], v[u].x, acc[0]);
                acc[1] = fmaf(m[u], v[u].y, acc[1]);
                acc[2] = fmaf(m[u], v[u].z, acc[2]);
                acc[3] = fmaf(m[u], v[u].w, acc[3]);
            }
        }
    }

    // butterfly-reduce across the 8 row groups (lanes sharing q end with chunk totals)
    #pragma unroll
    for (int off = 8; off < 64; off <<= 1)
        #pragma unroll
        for (int c = 0; c < VW; ++c) acc[c] += __shfl_xor(acc[c], off);

    // add self row, scale by dinv[d], vector store (lanes grp==0: 64/128B coalesced)
    float dn = dinv[node];
    if constexpr (VW == 2) {
        float2 v = reinterpret_cast<const float2*>(g)[(size_t)node * 8 + q];
        float2 o;
        o.x = dn * (acc[0] + v.x);
        o.y = dn * (acc[1] + v.y);
        if (grp == 0) reinterpret_cast<float2*>(pre)[(size_t)node * 8 + q] = o;
    } else {
        float4 v = reinterpret_cast<const float4*>(g)[(size_t)node * 8 + q];
        float4 o;
        o.x = dn * (acc[0] + v.x);
        o.y = dn * (acc[1] + v.y);
        o.z = dn * (acc[2] + v.z);
        o.w = dn * (acc[3] + v.w);
        if (grp == 0) reinterpret_cast<float4*>(pre)[(size_t)node * 8 + q] = o;
    }
}

// ---------------- post-agg linear (thread-per-node): out = [relu](pre @ W + b) [* dinv] -----
// W is FINR x FOUT row-major; LDS-padded to FINP x FOUT (pad rows zeroed).

template <int FINP, int FINR, int FOUT, bool RELU, bool SCALE>
__global__ void linear_kernel(const float* __restrict__ pre, const float* __restrict__ W,
                              const float* __restrict__ bias, const float* __restrict__ dinv,
                              float* __restrict__ out, int n) {
    __shared__ float sW[FINP * FOUT];
    __shared__ float sB[FOUT];
    for (int i = threadIdx.x; i < FINP * FOUT; i += blockDim.x)
        sW[i] = (i < FINR * FOUT) ? W[i] : 0.f;
    for (int i = threadIdx.x; i < FOUT; i += blockDim.x) sB[i] = bias[i];
    __syncthreads();
    int node = blockIdx.x * blockDim.x + threadIdx.x;
    if (node >= n) return;
    float xi[FINP];
    #pragma unroll
    for (int k = 0; k < FINP; ++k) xi[k] = pre[(size_t)node * FINP + k];
    float s = SCALE ? dinv[node] : 1.f;
    #pragma unroll
    for (int fo = 0; fo < FOUT; ++fo) {
        float acc = sB[fo];
        #pragma unroll
        for (int k = 0; k < FINP; ++k) acc = fmaf(xi[k], sW[k * FOUT + fo], acc);
        if (RELU) acc = fmaxf(acc, 0.f);
        out[(size_t)node * FOUT + fo] = acc * s;
    }
}

// ---------------- launch ----------------

extern "C" void kernel_launch(void* const* d_in, const int* in_sizes, int n_in,
                              void* d_out, int out_size, void* d_ws, size_t ws_size,
                              hipStream_t stream) {
    const float* x  = (const float*)d_in[0];
    const int*   ei = (const int*)d_in[1];
    const float* W1 = (const float*)d_in[2];
    const float* b1 = (const float*)d_in[3];
    const float* W2 = (const float*)d_in[4];
    const float* b2 = (const float*)d_in[5];
    const float* W3 = (const float*)d_in[6];
    const float* b3 = (const float*)d_in[7];
    float* out = (float*)d_out;

    const int n = in_sizes[0] / 11;   // 100000
    const int E = in_sizes[1] / 2;    // 3200000
    const int* src = ei;
    const int* dst = ei + E;

    const int nbkt = (n + NPB - 1) >> NPB_SHIFT;        // 782
    const int HBr  = (E + CHUNK - 1) / CHUNK;           // 782
    const size_t len = (size_t)nbkt * HBr;              // 611,524
    const int nb = (int)((len + 8191) / 8192);          // 75 (<=128)

    char* ws = (char*)d_ws;
    size_t off = 0;
    auto alloc = [&](size_t bytes) {
        void* p = ws + off;
        off = (off + bytes + 255) & ~(size_t)255;
        return p;
    };
    int*   offbuf    = (int*)  alloc(len * 4);
    int*   partial   = (int*)  alloc((size_t)128 * 4);
    int*   ebuf      = (int*)  alloc((size_t)E * 4);
    int*   csr_src   = (int*)  alloc((size_t)E * 4);
    int*   row_start = (int*)  alloc((size_t)(n + 1) * 4);
    float* dinv      = (float*)alloc((size_t)n * 4);
    float* g0        = (float*)alloc((size_t)n * 16 * 4);
    float* g1        = (float*)alloc((size_t)n * 16 * 4);
    float* preS      = (float*)alloc((size_t)n * 16 * 4);  // pre1 / pre2
    float* g2        = (float*)alloc((size_t)n * 32 * 4);
    float* preL      = (float*)alloc((size_t)n * 32 * 4);  // pre3
    (void)ws_size;

    const int B = 256;
    int gn   = (n + B - 1) / B;
    int glen = (int)((len + B - 1) / B);
    int gagg = (n + 3) / 4;           // one wave per node

    // ---- atomic-free CSR build ----
    hist_kernel<<<HBr, B, 0, stream>>>(dst, offbuf, E, HBr, nbkt);
    scan_block8_kernel<<<nb, 1024, 0, stream>>>(offbuf, partial, (int)len);
    scan_partials_kernel<<<1, 64, 0, stream>>>(partial, nb);
    add_base_kernel<<<glen, B, 0, stream>>>(offbuf, partial, (int)len);
    scatter_kernel<<<HBr, B, 0, stream>>>(src, dst, offbuf, ebuf, E, HBr, nbkt);
    bucket_build_kernel<<<nbkt, B, 0, stream>>>(ebuf, offbuf, csr_src, row_start, dinv, E, HBr, nbkt, n);

    // ---- g0 = pad16(x) * dinv ----
    pad_scale_kernel<<<gn, B, 0, stream>>>(x, dinv, g0, n);

    // layer 1: agg(16-wide, 11 real) -> linear 11->16, relu, scale
    aggregate_kernel<16><<<gagg, B, 0, stream>>>(g0, row_start, csr_src, dinv, preS, n);
    linear_kernel<16, 11, 16, true, true><<<gn, B, 0, stream>>>(preS, W1, b1, dinv, g1, n);

    // layer 2: agg(16) -> linear 16->32, relu, scale
    aggregate_kernel<16><<<gagg, B, 0, stream>>>(g1, row_start, csr_src, dinv, preS, n);
    linear_kernel<16, 16, 32, true, true><<<gn, B, 0, stream>>>(preS, W2, b2, dinv, g2, n);

    // layer 3: agg(32) -> linear 32->64, no relu, no scale
    aggregate_kernel<32><<<gagg, B, 0, stream>>>(g2, row_start, csr_src, dinv, preL, n);
    linear_kernel<32, 32, 64, false, false><<<gn, B, 0, stream>>>(preL, W3, b3, dinv, out, n);
}

// Round 11
// 228.775 us; speedup vs baseline: 1.0620x; 1.0620x over previous
//
#include <hip/hip_runtime.h>

// ---- bucket-sort CSR parameters (n <= 131072, so src/dst fit in 17 bits) ----
#define NPB_SHIFT 7
#define NPB       128      // nodes per bucket
#define CHUNK     4096     // edges per hist/scatter block (16 per thread)
#define STAGE_CAP 8192     // bucket_build LDS staging (ints); avg bucket ~4092
#define NBKT_MAX  1024     // LDS bin cap (needs nbkt <= 1024)

// ---------------- pass 1: per-block LDS histogram of dst buckets ----------------

__global__ void hist_kernel(const int* __restrict__ dst, int* __restrict__ hist,
                            int E, int HBr, int nbkt) {
    __shared__ int bins[NBKT_MAX];
    int tid = threadIdx.x;
    for (int i = tid; i < nbkt; i += 256) bins[i] = 0;
    __syncthreads();
    int start = blockIdx.x * CHUNK;
    #pragma unroll
    for (int j = 0; j < 16; ++j) {
        int e = start + j * 256 + tid;
        if (e < E) atomicAdd(&bins[dst[e] >> NPB_SHIFT], 1);
    }
    __syncthreads();
    for (int i = tid; i < nbkt; i += 256)
        hist[(size_t)i * HBr + blockIdx.x] = bins[i];
}

// ---------------- 2-phase exclusive scan over hist matrix (in place; base added by consumers) --

__global__ void scan_block8_kernel(int* data, int* __restrict__ partial, int len) {
    __shared__ int wtot[16];
    int tid = threadIdx.x, lane = tid & 63, wid = tid >> 6;
    int base = blockIdx.x * 8192 + tid * 8;
    int v[8]; int s = 0;
    #pragma unroll
    for (int j = 0; j < 8; ++j) {
        int i = base + j;
        v[j] = (i < len) ? data[i] : 0;
        s += v[j];
    }
    int inc = s;
    #pragma unroll
    for (int o = 1; o < 64; o <<= 1) { int t = __shfl_up(inc, o); if (lane >= o) inc += t; }
    if (lane == 63) wtot[wid] = inc;
    __syncthreads();
    if (tid == 0) {
        int run = 0;
        #pragma unroll
        for (int w = 0; w < 16; ++w) { int t = wtot[w]; wtot[w] = run; run += t; }
        partial[blockIdx.x] = run;
    }
    __syncthreads();
    int excl = wtot[wid] + inc - s;
    #pragma unroll
    for (int j = 0; j < 8; ++j) {
        int i = base + j;
        if (i < len) data[i] = excl;
        excl += v[j];
    }
}

__global__ void scan_partials_kernel(int* partial, int nb) {
    int t = threadIdx.x;  // 64 threads; nb <= 128
    int i0 = 2 * t, i1 = 2 * t + 1;
    int v0 = (i0 < nb) ? partial[i0] : 0;
    int v1 = (i1 < nb) ? partial[i1] : 0;
    int s = v0 + v1;
    int inc = s;
    #pragma unroll
    for (int o = 1; o < 64; o <<= 1) { int u = __shfl_up(inc, o); if (t >= o) inc += u; }
    int excl = inc - s;
    if (i0 < nb) partial[i0] = excl;
    if (i1 < nb) partial[i1] = excl + v0;
}

// ---------------- pass 2: tile-sort scatter into bucket-ordered ebuf ----------------
// payload packed: (dst & 127) << 17 | src   (src < 2^17)
// global offsets = offbuf[..] + partial[idx>>13]  (base folded in here)

__global__ void scatter_kernel(const int* __restrict__ src, const int* __restrict__ dst,
                               const int* __restrict__ offbuf, const int* __restrict__ partial,
                               int* __restrict__ ebuf, int E, int HBr, int nbkt) {
    __shared__ int gbase[NBKT_MAX];
    __shared__ int thist[NBKT_MAX];
    __shared__ int toff[NBKT_MAX + 1];
    __shared__ int stage[CHUNK];
    __shared__ unsigned short bstage[CHUNK];
    __shared__ int wtot4[4];
    int tid = threadIdx.x, lane = tid & 63, wid = tid >> 6;
    for (int i = tid; i < nbkt; i += 256) {
        size_t idx = (size_t)i * HBr + blockIdx.x;
        gbase[i] = offbuf[idx] + partial[(int)(idx >> 13)];
    }
    for (int i = tid; i < NBKT_MAX; i += 256) thist[i] = 0;
    __syncthreads();
    int start = blockIdx.x * CHUNK;
    int s_[16], d_[16], r_[16];
    #pragma unroll
    for (int j = 0; j < 16; ++j) {
        int e = start + j * 256 + tid;
        if (e < E) {
            s_[j] = src[e];
            d_[j] = dst[e];
            r_[j] = atomicAdd(&thist[d_[j] >> NPB_SHIFT], 1);
        } else {
            d_[j] = -1;
        }
    }
    __syncthreads();
    int a0 = thist[4 * tid], a1 = thist[4 * tid + 1],
        a2 = thist[4 * tid + 2], a3 = thist[4 * tid + 3];
    int ss = a0 + a1 + a2 + a3;
    int inc = ss;
    #pragma unroll
    for (int o = 1; o < 64; o <<= 1) { int t = __shfl_up(inc, o); if (lane >= o) inc += t; }
    if (lane == 63) wtot4[wid] = inc;
    __syncthreads();
    int wbase = 0;
    for (int w = 0; w < wid; ++w) wbase += wtot4[w];
    int excl = wbase + inc - ss;
    toff[4 * tid]     = excl;
    toff[4 * tid + 1] = excl + a0;
    toff[4 * tid + 2] = excl + a0 + a1;
    toff[4 * tid + 3] = excl + a0 + a1 + a2;
    if (tid == 255) toff[1024] = excl + ss;  // total valid
    __syncthreads();
    #pragma unroll
    for (int j = 0; j < 16; ++j) {
        if (d_[j] >= 0) {
            int b = d_[j] >> NPB_SHIFT;
            int q = toff[b] + r_[j];
            stage[q]  = ((d_[j] & (NPB - 1)) << 17) | s_[j];
            bstage[q] = (unsigned short)b;
        }
    }
    __syncthreads();
    int total = toff[1024];
    for (int j = tid; j < total; j += 256) {
        int b = bstage[j];
        ebuf[gbase[b] + (j - toff[b])] = stage[j];
    }
}

// ---------------- pass 3: per-bucket CSR build + row_start + dinv + fused pad_scale ---------
// Single global read of ebuf: each thread keeps its <=20 edges in registers through
// count -> scan -> place. Also writes g0 = pad16(x)*dinv for this bucket's nodes.

__global__ void bucket_build_kernel(const int* __restrict__ ebuf, const int* __restrict__ offbuf,
                                    const int* __restrict__ partial, const float* __restrict__ x,
                                    int* __restrict__ csr_src, int* __restrict__ row_start,
                                    float* __restrict__ dinv, float* __restrict__ g0,
                                    int E, int HBr, int nbkt, int n) {
    __shared__ int cnt[NPB], cur[NPB];
    __shared__ float dnl[NPB];
    __shared__ int stage[STAGE_CAP];
    __shared__ int wtot2[2];
    int tid = threadIdx.x;
    int k = blockIdx.x;
    size_t ib = (size_t)k * HBr;
    int bb = offbuf[ib] + partial[(int)(ib >> 13)];
    int be;
    if (k + 1 < nbkt) {
        size_t ie = (size_t)(k + 1) * HBr;
        be = offbuf[ie] + partial[(int)(ie >> 13)];
    } else be = E;
    int bsize = be - bb;
    if (tid < NPB) cnt[tid] = 0;
    __syncthreads();

    constexpr int J = 20;                       // 20*256 = 5120 edge cap (avg 4092, sigma~64)
    int v[J], r[J];
    bool fast = (bsize <= J * 256) && (bsize <= STAGE_CAP);
    if (fast) {
        #pragma unroll
        for (int j = 0; j < J; ++j) {
            int e = bb + tid + j * 256;
            if (e < be) { v[j] = ebuf[e]; r[j] = atomicAdd(&cnt[v[j] >> 17], 1); }
            else v[j] = -1;
        }
    } else {
        for (int e = bb + tid; e < be; e += 256) atomicAdd(&cnt[ebuf[e] >> 17], 1);
    }
    __syncthreads();

    int lane = tid & 63, wid = tid >> 6;
    int c = 0, inc = 0;
    if (tid < NPB) {                            // waves 0,1 entirely inside
        c = cnt[tid];
        inc = c;
        #pragma unroll
        for (int o = 1; o < 64; o <<= 1) { int t = __shfl_up(inc, o); if (lane >= o) inc += t; }
        if (lane == 63) wtot2[wid] = inc;
    }
    __syncthreads();
    if (tid < NPB) {
        int base = (wid == 1) ? wtot2[0] : 0;
        int excl = base + inc - c;
        cur[tid] = excl;
        int node = k * NPB + tid;
        if (node < n) {
            row_start[node] = bb + excl;
            float dn = rsqrtf((float)(c + 1));  // self-loop
            dinv[node] = dn;
            dnl[tid] = dn;
        }
    }
    if (k == 0 && tid == 0) row_start[n] = E;
    __syncthreads();

    // fused pad_scale: g0[node][kk] = (kk<11) ? x[node][kk]*dinv[node] : 0
    {
        int base_node = k * NPB;
        for (int i = tid; i < NPB * 16; i += 256) {
            int ln = i >> 4, kk = i & 15;
            int node = base_node + ln;
            if (node < n)
                g0[(size_t)node * 16 + kk] = (kk < 11) ? x[(size_t)node * 11 + kk] * dnl[ln] : 0.f;
        }
    }

    if (fast) {
        #pragma unroll
        for (int j = 0; j < J; ++j)
            if (v[j] >= 0) stage[cur[v[j] >> 17] + r[j]] = v[j] & 0x1FFFF;
        __syncthreads();
        for (int j = tid; j < bsize; j += 256) csr_src[bb + j] = stage[j];  // coalesced
    } else if (bsize <= STAGE_CAP) {
        for (int e = bb + tid; e < be; e += 256) {
            int vv = ebuf[e];
            int rr = atomicAdd(&cur[vv >> 17], 1);
            stage[rr] = vv & 0x1FFFF;
        }
        __syncthreads();
        for (int j = tid; j < bsize; j += 256) csr_src[bb + j] = stage[j];
    } else {
        for (int e = bb + tid; e < be; e += 256) {
            int vv = ebuf[e];
            int rr = atomicAdd(&cur[vv >> 17], 1);
            csr_src[bb + rr] = vv & 0x1FFFF;
        }
    }
}

// ---------------- gather-aggregate (vectorized, deg-adaptive) ----------------
// pre[d] = dinv[d] * (sum_{s in N(d)} g[s] + g[d]);  g rows carry dinv[s].
// 8 lanes/row (float2 FIN=16, float4 FIN=32); 8 rows per load instruction.
// Full unmasked batches while >=64 remain; masked tail uses 4 instrs if nrem<=32
// (covers >half of Poisson(32) nodes) else 8 — saves wasted clamp-gather issue.

template <int VW, int NB>
__device__ inline void gather_batch(const float* __restrict__ g, const int* __restrict__ csr_src,
                                    int p, int end, int nrem, int node, int q, int grp,
                                    float* acc) {
    int   s[NB];
    float m[NB];
    #pragma unroll
    for (int u = 0; u < NB; ++u) {
        int slot = u * 8 + grp;
        s[u] = csr_src[min(p + slot, end - 1)];           // clamped, in-bounds
        m[u] = (slot < nrem) ? 1.f : 0.f;
    }
    if constexpr (VW == 2) {
        const float2* gv = reinterpret_cast<const float2*>(g);
        float2 v[NB];
        #pragma unroll
        for (int u = 0; u < NB; ++u) v[u] = gv[(size_t)s[u] * 8 + q];
        #pragma unroll
        for (int u = 0; u < NB; ++u) {
            acc[0] = fmaf(m[u], v[u].x, acc[0]);
            acc[1] = fmaf(m[u], v[u].y, acc[1]);
        }
    } else {
        const float4* gv = reinterpret_cast<const float4*>(g);
        float4 v[NB];
        #pragma unroll
        for (int u = 0; u < NB; ++u) v[u] = gv[(size_t)s[u] * 8 + q];
        #pragma unroll
        for (int u = 0; u < NB; ++u) {
            acc[0] = fmaf(m[u], v[u].x, acc[0]);
            acc[1] = fmaf(m[u], v[u].y, acc[1]);
            acc[2] = fmaf(m[u], v[u].z, acc[2]);
            acc[3] = fmaf(m[u], v[u].w, acc[3]);
        }
    }
}

template <int FOUT>
__global__ void aggregate_kernel(const float* __restrict__ g,
                                 const int* __restrict__ row_start,
                                 const int* __restrict__ csr_src,
                                 const float* __restrict__ dinv,
                                 float* __restrict__ pre, int n) {
    constexpr int VW = FOUT / 8;   // floats per lane (2 or 4)
    int lane = threadIdx.x & 63;
    int wid  = threadIdx.x >> 6;
    int node = blockIdx.x * (blockDim.x >> 6) + wid;
    if (node >= n) return;
    int q   = lane & 7;        // chunk index within row
    int grp = lane >> 3;       // row slot within each 8-row group
    int beg = row_start[node];
    int end = row_start[node + 1];
    float acc[VW];
    #pragma unroll
    for (int c = 0; c < VW; ++c) acc[c] = 0.f;

    int p = beg;
    // unmasked full batches
    for (; p + 64 <= end; p += 64) {
        int s[8];
        #pragma unroll
        for (int u = 0; u < 8; ++u) s[u] = csr_src[p + u * 8 + grp];  // broadcast x8 lanes
        if constexpr (VW == 2) {
            const float2* gv = reinterpret_cast<const float2*>(g);
            float2 v[8];
            #pragma unroll
            for (int u = 0; u < 8; ++u) v[u] = gv[(size_t)s[u] * 8 + q];
            #pragma unroll
            for (int u = 0; u < 8; ++u) { acc[0] += v[u].x; acc[1] += v[u].y; }
        } else {
            const float4* gv = reinterpret_cast<const float4*>(g);
            float4 v[8];
            #pragma unroll
            for (int u = 0; u < 8; ++u) v[u] = gv[(size_t)s[u] * 8 + q];
            #pragma unroll
            for (int u = 0; u < 8; ++u) {
                acc[0] += v[u].x; acc[1] += v[u].y; acc[2] += v[u].z; acc[3] += v[u].w;
            }
        }
    }
    // masked tail: 4 instrs covers nrem<=32 (majority), else 8
    int nrem = end - p;
    if (nrem > 0) {
        if (nrem <= 32) gather_batch<VW, 4>(g, csr_src, p, end, nrem, node, q, grp, acc);
        else            gather_batch<VW, 8>(g, csr_src, p, end, nrem, node, q, grp, acc);
    }

    // butterfly-reduce across the 8 row groups
    #pragma unroll
    for (int off = 8; off < 64; off <<= 1)
        #pragma unroll
        for (int c = 0; c < VW; ++c) acc[c] += __shfl_xor(acc[c], off);

    // add self row, scale by dinv[d], vector store (lanes grp==0: 64/128B coalesced)
    float dn = dinv[node];
    if constexpr (VW == 2) {
        float2 v = reinterpret_cast<const float2*>(g)[(size_t)node * 8 + q];
        float2 o;
        o.x = dn * (acc[0] + v.x);
        o.y = dn * (acc[1] + v.y);
        if (grp == 0) reinterpret_cast<float2*>(pre)[(size_t)node * 8 + q] = o;
    } else {
        float4 v = reinterpret_cast<const float4*>(g)[(size_t)node * 8 + q];
        float4 o;
        o.x = dn * (acc[0] + v.x);
        o.y = dn * (acc[1] + v.y);
        o.z = dn * (acc[2] + v.z);
        o.w = dn * (acc[3] + v.w);
        if (grp == 0) reinterpret_cast<float4*>(pre)[(size_t)node * 8 + q] = o;
    }
}

// ---------------- post-agg linear (thread-per-node): out = [relu](pre @ W + b) [* dinv] -----

template <int FINP, int FINR, int FOUT, bool RELU, bool SCALE>
__global__ void linear_kernel(const float* __restrict__ pre, const float* __restrict__ W,
                              const float* __restrict__ bias, const float* __restrict__ dinv,
                              float* __restrict__ out, int n) {
    __shared__ float sW[FINP * FOUT];
    __shared__ float sB[FOUT];
    for (int i = threadIdx.x; i < FINP * FOUT; i += blockDim.x)
        sW[i] = (i < FINR * FOUT) ? W[i] : 0.f;
    for (int i = threadIdx.x; i < FOUT; i += blockDim.x) sB[i] = bias[i];
    __syncthreads();
    int node = blockIdx.x * blockDim.x + threadIdx.x;
    if (node >= n) return;
    float xi[FINP];
    #pragma unroll
    for (int k = 0; k < FINP; ++k) xi[k] = pre[(size_t)node * FINP + k];
    float s = SCALE ? dinv[node] : 1.f;
    #pragma unroll
    for (int fo = 0; fo < FOUT; ++fo) {
        float acc = sB[fo];
        #pragma unroll
        for (int k = 0; k < FINP; ++k) acc = fmaf(xi[k], sW[k * FOUT + fo], acc);
        if (RELU) acc = fmaxf(acc, 0.f);
        out[(size_t)node * FOUT + fo] = acc * s;
    }
}

// ---------------- launch ----------------

extern "C" void kernel_launch(void* const* d_in, const int* in_sizes, int n_in,
                              void* d_out, int out_size, void* d_ws, size_t ws_size,
                              hipStream_t stream) {
    const float* x  = (const float*)d_in[0];
    const int*   ei = (const int*)d_in[1];
    const float* W1 = (const float*)d_in[2];
    const float* b1 = (const float*)d_in[3];
    const float* W2 = (const float*)d_in[4];
    const float* b2 = (const float*)d_in[5];
    const float* W3 = (const float*)d_in[6];
    const float* b3 = (const float*)d_in[7];
    float* out = (float*)d_out;

    const int n = in_sizes[0] / 11;   // 100000
    const int E = in_sizes[1] / 2;    // 3200000
    const int* src = ei;
    const int* dst = ei + E;

    const int nbkt = (n + NPB - 1) >> NPB_SHIFT;        // 782
    const int HBr  = (E + CHUNK - 1) / CHUNK;           // 782
    const size_t len = (size_t)nbkt * HBr;              // 611,524
    const int nb = (int)((len + 8191) / 8192);          // 75 (<=128)

    char* ws = (char*)d_ws;
    size_t off = 0;
    auto alloc = [&](size_t bytes) {
        void* p = ws + off;
        off = (off + bytes + 255) & ~(size_t)255;
        return p;
    };
    int*   offbuf    = (int*)  alloc(len * 4);
    int*   partial   = (int*)  alloc((size_t)128 * 4);
    int*   ebuf      = (int*)  alloc((size_t)E * 4);
    int*   csr_src   = (int*)  alloc((size_t)E * 4);
    int*   row_start = (int*)  alloc((size_t)(n + 1) * 4);
    float* dinv      = (float*)alloc((size_t)n * 4);
    float* g0        = (float*)alloc((size_t)n * 16 * 4);
    float* g1        = (float*)alloc((size_t)n * 16 * 4);
    float* preS      = (float*)alloc((size_t)n * 16 * 4);  // pre1 / pre2
    float* g2        = (float*)alloc((size_t)n * 32 * 4);
    float* preL      = (float*)alloc((size_t)n * 32 * 4);  // pre3
    (void)ws_size;

    const int B = 256;
    int gn   = (n + B - 1) / B;
    int gagg = (n + 3) / 4;           // one wave per node

    // ---- atomic-free CSR build (+ fused dinv/row_start/pad_scale) ----
    hist_kernel<<<HBr, B, 0, stream>>>(dst, offbuf, E, HBr, nbkt);
    scan_block8_kernel<<<nb, 1024, 0, stream>>>(offbuf, partial, (int)len);
    scan_partials_kernel<<<1, 64, 0, stream>>>(partial, nb);
    scatter_kernel<<<HBr, B, 0, stream>>>(src, dst, offbuf, partial, ebuf, E, HBr, nbkt);
    bucket_build_kernel<<<nbkt, B, 0, stream>>>(ebuf, offbuf, partial, x, csr_src, row_start,
                                                dinv, g0, E, HBr, nbkt, n);

    // layer 1: agg(16-wide, 11 real) -> linear 11->16, relu, scale
    aggregate_kernel<16><<<gagg, B, 0, stream>>>(g0, row_start, csr_src, dinv, preS, n);
    linear_kernel<16, 11, 16, true, true><<<gn, B, 0, stream>>>(preS, W1, b1, dinv, g1, n);

    // layer 2: agg(16) -> linear 16->32, relu, scale
    aggregate_kernel<16><<<gagg, B, 0, stream>>>(g1, row_start, csr_src, dinv, preS, n);
    linear_kernel<16, 16, 32, true, true><<<gn, B, 0, stream>>>(preS, W2, b2, dinv, g2, n);

    // layer 3: agg(32) -> linear 32->64, no relu, no scale
    aggregate_kernel<32><<<gagg, B, 0, stream>>>(g2, row_start, csr_src, dinv, preL, n);
    linear_kernel<32, 32, 64, false, false><<<gn, B, 0, stream>>>(preL, W3, b3, dinv, out, n);
}

// Round 12
// 201.100 us; speedup vs baseline: 1.2082x; 1.1376x over previous
//
#include <hip/hip_runtime.h>
#include <hip/hip_fp16.h>

// ---- bucket-sort CSR parameters (n <= 131072, so src/dst fit in 17 bits) ----
#define NPB_SHIFT 7
#define NPB       128      // nodes per bucket
#define CHUNK     4096     // edges per hist/scatter block (16 per thread)
#define STAGE_CAP 8192     // bucket_build LDS staging (ints); avg bucket ~4092
#define NBKT_MAX  1024     // LDS bin cap (needs nbkt <= 1024)

union U2H { unsigned u; __half2 h; };

__device__ inline float2 h2f(unsigned u) {
    U2H c; c.u = u;
    return __half22float2(c.h);
}

__device__ inline unsigned f2h(float a, float b) {
    U2H c; c.h = __float22half2_rn(make_float2(a, b));
    return c.u;
}

// ---------------- pass 1: per-block LDS histogram of dst buckets ----------------

__global__ void hist_kernel(const int* __restrict__ dst, int* __restrict__ hist,
                            int E, int HBr, int nbkt) {
    __shared__ int bins[NBKT_MAX];
    int tid = threadIdx.x;
    for (int i = tid; i < nbkt; i += 256) bins[i] = 0;
    __syncthreads();
    int start = blockIdx.x * CHUNK;
    #pragma unroll
    for (int j = 0; j < 16; ++j) {
        int e = start + j * 256 + tid;
        if (e < E) atomicAdd(&bins[dst[e] >> NPB_SHIFT], 1);
    }
    __syncthreads();
    for (int i = tid; i < nbkt; i += 256)
        hist[(size_t)i * HBr + blockIdx.x] = bins[i];
}

// ---------------- 2-phase exclusive scan over hist matrix (in place) ----------------

__global__ void scan_block8_kernel(int* data, int* __restrict__ partial, int len) {
    __shared__ int wtot[16];
    int tid = threadIdx.x, lane = tid & 63, wid = tid >> 6;
    int base = blockIdx.x * 8192 + tid * 8;
    int v[8]; int s = 0;
    #pragma unroll
    for (int j = 0; j < 8; ++j) {
        int i = base + j;
        v[j] = (i < len) ? data[i] : 0;
        s += v[j];
    }
    int inc = s;
    #pragma unroll
    for (int o = 1; o < 64; o <<= 1) { int t = __shfl_up(inc, o); if (lane >= o) inc += t; }
    if (lane == 63) wtot[wid] = inc;
    __syncthreads();
    if (tid == 0) {
        int run = 0;
        #pragma unroll
        for (int w = 0; w < 16; ++w) { int t = wtot[w]; wtot[w] = run; run += t; }
        partial[blockIdx.x] = run;
    }
    __syncthreads();
    int excl = wtot[wid] + inc - s;
    #pragma unroll
    for (int j = 0; j < 8; ++j) {
        int i = base + j;
        if (i < len) data[i] = excl;
        excl += v[j];
    }
}

__global__ void scan_partials_kernel(int* partial, int nb) {
    int t = threadIdx.x;  // 64 threads; nb <= 128
    int i0 = 2 * t, i1 = 2 * t + 1;
    int v0 = (i0 < nb) ? partial[i0] : 0;
    int v1 = (i1 < nb) ? partial[i1] : 0;
    int s = v0 + v1;
    int inc = s;
    #pragma unroll
    for (int o = 1; o < 64; o <<= 1) { int u = __shfl_up(inc, o); if (t >= o) inc += u; }
    int excl = inc - s;
    if (i0 < nb) partial[i0] = excl;
    if (i1 < nb) partial[i1] = excl + v0;
}

// ---------------- pass 2: tile-sort scatter into bucket-ordered ebuf ----------------

__global__ void scatter_kernel(const int* __restrict__ src, const int* __restrict__ dst,
                               const int* __restrict__ offbuf, const int* __restrict__ partial,
                               int* __restrict__ ebuf, int E, int HBr, int nbkt) {
    __shared__ int gbase[NBKT_MAX];
    __shared__ int thist[NBKT_MAX];
    __shared__ int toff[NBKT_MAX + 1];
    __shared__ int stage[CHUNK];
    __shared__ unsigned short bstage[CHUNK];
    __shared__ int wtot4[4];
    int tid = threadIdx.x, lane = tid & 63, wid = tid >> 6;
    for (int i = tid; i < nbkt; i += 256) {
        size_t idx = (size_t)i * HBr + blockIdx.x;
        gbase[i] = offbuf[idx] + partial[(int)(idx >> 13)];
    }
    for (int i = tid; i < NBKT_MAX; i += 256) thist[i] = 0;
    __syncthreads();
    int start = blockIdx.x * CHUNK;
    int s_[16], d_[16], r_[16];
    #pragma unroll
    for (int j = 0; j < 16; ++j) {
        int e = start + j * 256 + tid;
        if (e < E) {
            s_[j] = src[e];
            d_[j] = dst[e];
            r_[j] = atomicAdd(&thist[d_[j] >> NPB_SHIFT], 1);
        } else {
            d_[j] = -1;
        }
    }
    __syncthreads();
    int a0 = thist[4 * tid], a1 = thist[4 * tid + 1],
        a2 = thist[4 * tid + 2], a3 = thist[4 * tid + 3];
    int ss = a0 + a1 + a2 + a3;
    int inc = ss;
    #pragma unroll
    for (int o = 1; o < 64; o <<= 1) { int t = __shfl_up(inc, o); if (lane >= o) inc += t; }
    if (lane == 63) wtot4[wid] = inc;
    __syncthreads();
    int wbase = 0;
    for (int w = 0; w < wid; ++w) wbase += wtot4[w];
    int excl = wbase + inc - ss;
    toff[4 * tid]     = excl;
    toff[4 * tid + 1] = excl + a0;
    toff[4 * tid + 2] = excl + a0 + a1;
    toff[4 * tid + 3] = excl + a0 + a1 + a2;
    if (tid == 255) toff[1024] = excl + ss;  // total valid
    __syncthreads();
    #pragma unroll
    for (int j = 0; j < 16; ++j) {
        if (d_[j] >= 0) {
            int b = d_[j] >> NPB_SHIFT;
            int q = toff[b] + r_[j];
            stage[q]  = ((d_[j] & (NPB - 1)) << 17) | s_[j];
            bstage[q] = (unsigned short)b;
        }
    }
    __syncthreads();
    int total = toff[1024];
    for (int j = tid; j < total; j += 256) {
        int b = bstage[j];
        ebuf[gbase[b] + (j - toff[b])] = stage[j];
    }
}

// ---------------- pass 3: per-bucket CSR build + row_start + dinv + fused pad_scale (fp16) --

__global__ void bucket_build_kernel(const int* __restrict__ ebuf, const int* __restrict__ offbuf,
                                    const int* __restrict__ partial, const float* __restrict__ x,
                                    int* __restrict__ csr_src, int* __restrict__ row_start,
                                    float* __restrict__ dinv, unsigned* __restrict__ g0h,
                                    int E, int HBr, int nbkt, int n) {
    __shared__ int cnt[NPB], cur[NPB];
    __shared__ float dnl[NPB];
    __shared__ int stage[STAGE_CAP];
    __shared__ int wtot2[2];
    int tid = threadIdx.x;
    int k = blockIdx.x;
    size_t ib = (size_t)k * HBr;
    int bb = offbuf[ib] + partial[(int)(ib >> 13)];
    int be;
    if (k + 1 < nbkt) {
        size_t ie = (size_t)(k + 1) * HBr;
        be = offbuf[ie] + partial[(int)(ie >> 13)];
    } else be = E;
    int bsize = be - bb;
    if (tid < NPB) cnt[tid] = 0;
    __syncthreads();

    constexpr int J = 20;                       // 20*256 = 5120 edge cap (avg 4092)
    int v[J], r[J];
    bool fast = (bsize <= J * 256) && (bsize <= STAGE_CAP);
    if (fast) {
        #pragma unroll
        for (int j = 0; j < J; ++j) {
            int e = bb + tid + j * 256;
            if (e < be) { v[j] = ebuf[e]; r[j] = atomicAdd(&cnt[v[j] >> 17], 1); }
            else v[j] = -1;
        }
    } else {
        for (int e = bb + tid; e < be; e += 256) atomicAdd(&cnt[ebuf[e] >> 17], 1);
    }
    __syncthreads();

    int lane = tid & 63, wid = tid >> 6;
    int c = 0, inc = 0;
    if (tid < NPB) {
        c = cnt[tid];
        inc = c;
        #pragma unroll
        for (int o = 1; o < 64; o <<= 1) { int t = __shfl_up(inc, o); if (lane >= o) inc += t; }
        if (lane == 63) wtot2[wid] = inc;
    }
    __syncthreads();
    if (tid < NPB) {
        int base = (wid == 1) ? wtot2[0] : 0;
        int excl = base + inc - c;
        cur[tid] = excl;
        int node = k * NPB + tid;
        if (node < n) {
            row_start[node] = bb + excl;
            float dn = rsqrtf((float)(c + 1));  // self-loop
            dinv[node] = dn;
            dnl[tid] = dn;
        }
    }
    if (k == 0 && tid == 0) row_start[n] = E;
    __syncthreads();

    // fused pad_scale into fp16: g0[node] = half(pad16(x[node]) * dinv[node])
    {
        int base_node = k * NPB;
        for (int i = tid; i < NPB * 8; i += 256) {
            int ln = i >> 3, kk = i & 7;
            int node = base_node + ln;
            if (node < n) {
                float dn = dnl[ln];
                int f0 = 2 * kk, f1 = f0 + 1;
                float a = (f0 < 11) ? x[(size_t)node * 11 + f0] * dn : 0.f;
                float b = (f1 < 11) ? x[(size_t)node * 11 + f1] * dn : 0.f;
                g0h[(size_t)node * 8 + kk] = f2h(a, b);
            }
        }
    }

    if (fast) {
        #pragma unroll
        for (int j = 0; j < J; ++j)
            if (v[j] >= 0) stage[cur[v[j] >> 17] + r[j]] = v[j] & 0x1FFFF;
        __syncthreads();
        for (int j = tid; j < bsize; j += 256) csr_src[bb + j] = stage[j];  // coalesced
    } else if (bsize <= STAGE_CAP) {
        for (int e = bb + tid; e < be; e += 256) {
            int vv = ebuf[e];
            int rr = atomicAdd(&cur[vv >> 17], 1);
            stage[rr] = vv & 0x1FFFF;
        }
        __syncthreads();
        for (int j = tid; j < bsize; j += 256) csr_src[bb + j] = stage[j];
    } else {
        for (int e = bb + tid; e < be; e += 256) {
            int vv = ebuf[e];
            int rr = atomicAdd(&cur[vv >> 17], 1);
            csr_src[bb + rr] = vv & 0x1FFFF;
        }
    }
}

// ---------------- gather-aggregate over fp16 tables, fp32 accumulation ----------------
// pre[d] = dinv[d] * (sum_{s in N(d)} g[s] + g[d]);  g rows carry dinv[s], stored fp16.
// Each lane reads one uint2 (4 halves). FIN=16: 4 lanes/row, 16 rows/instr;
// FIN=32: 8 lanes/row, 8 rows/instr. Deg-adaptive masked tail (1/2/4[/8] instrs).

template <int LPR, int NB>
__device__ inline void gather_batch_h(const uint2* __restrict__ gv, const int* __restrict__ csr,
                                      int p, int end, int nrem, int q, int grp, float* acc) {
    constexpr int NGRP = 64 / LPR;
    int s[NB]; float m[NB];
    #pragma unroll
    for (int u = 0; u < NB; ++u) {
        int slot = u * NGRP + grp;
        s[u] = csr[min(p + slot, end - 1)];               // clamped, in-bounds
        m[u] = (slot < nrem) ? 1.f : 0.f;
    }
    uint2 v[NB];
    #pragma unroll
    for (int u = 0; u < NB; ++u) v[u] = gv[(size_t)s[u] * LPR + q];
    #pragma unroll
    for (int u = 0; u < NB; ++u) {
        float2 a = h2f(v[u].x), b = h2f(v[u].y);
        acc[0] = fmaf(m[u], a.x, acc[0]);
        acc[1] = fmaf(m[u], a.y, acc[1]);
        acc[2] = fmaf(m[u], b.x, acc[2]);
        acc[3] = fmaf(m[u], b.y, acc[3]);
    }
}

template <int FIN>
__global__ void aggregate_kernel(const uint2* __restrict__ gv,
                                 const int* __restrict__ row_start,
                                 const int* __restrict__ csr_src,
                                 const float* __restrict__ dinv,
                                 float4* __restrict__ pre, int n) {
    constexpr int LPR  = FIN / 4;   // lanes per row (4 or 8)
    constexpr int NGRP = 64 / LPR;  // rows per load instruction (16 or 8)
    int lane = threadIdx.x & 63;
    int wid  = threadIdx.x >> 6;
    int node = blockIdx.x * (blockDim.x >> 6) + wid;
    if (node >= n) return;
    int q   = lane & (LPR - 1);
    int grp = lane / LPR;
    int beg = row_start[node];
    int end = row_start[node + 1];
    float acc[4] = {0.f, 0.f, 0.f, 0.f};

    int p = beg;
    // unmasked full 64-row batches (LPR instrs each)
    for (; p + 64 <= end; p += 64) {
        int s[LPR];
        #pragma unroll
        for (int u = 0; u < LPR; ++u) s[u] = csr_src[p + u * NGRP + grp];
        uint2 v[LPR];
        #pragma unroll
        for (int u = 0; u < LPR; ++u) v[u] = gv[(size_t)s[u] * LPR + q];
        #pragma unroll
        for (int u = 0; u < LPR; ++u) {
            float2 a = h2f(v[u].x), b = h2f(v[u].y);
            acc[0] += a.x; acc[1] += a.y; acc[2] += b.x; acc[3] += b.y;
        }
    }
    // deg-adaptive masked tail
    int nrem = end - p;
    if (nrem > 0) {
        if (nrem <= NGRP)          gather_batch_h<LPR, 1>(gv, csr_src, p, end, nrem, q, grp, acc);
        else if (nrem <= 2 * NGRP) gather_batch_h<LPR, 2>(gv, csr_src, p, end, nrem, q, grp, acc);
        else if (nrem <= 4 * NGRP) gather_batch_h<LPR, 4>(gv, csr_src, p, end, nrem, q, grp, acc);
        else if constexpr (LPR == 8)
                                   gather_batch_h<LPR, 8>(gv, csr_src, p, end, nrem, q, grp, acc);
    }

    // butterfly-reduce across row groups
    #pragma unroll
    for (int off = LPR; off < 64; off <<= 1)
        #pragma unroll
        for (int c = 0; c < 4; ++c) acc[c] += __shfl_xor(acc[c], off);

    // add self row, scale by dinv[d], vector store by lanes grp==0
    float dn = dinv[node];
    uint2 sv = gv[(size_t)node * LPR + q];
    float2 a = h2f(sv.x), b = h2f(sv.y);
    float4 o;
    o.x = dn * (acc[0] + a.x);
    o.y = dn * (acc[1] + a.y);
    o.z = dn * (acc[2] + b.x);
    o.w = dn * (acc[3] + b.y);
    if (grp == 0) pre[(size_t)node * LPR + q] = o;
}

// ---------------- post-agg linear (thread-per-node) ----------------
// out = [relu](pre @ W + b) [* dinv];  HALFOUT packs the result to fp16 pairs.

template <int FINP, int FINR, int FOUT, bool RELU, bool SCALE, bool HALFOUT>
__global__ void linear_kernel(const float* __restrict__ pre, const float* __restrict__ W,
                              const float* __restrict__ bias, const float* __restrict__ dinv,
                              void* __restrict__ outv, int n) {
    __shared__ float sW[FINP * FOUT];
    __shared__ float sB[FOUT];
    for (int i = threadIdx.x; i < FINP * FOUT; i += blockDim.x)
        sW[i] = (i < FINR * FOUT) ? W[i] : 0.f;
    for (int i = threadIdx.x; i < FOUT; i += blockDim.x) sB[i] = bias[i];
    __syncthreads();
    int node = blockIdx.x * blockDim.x + threadIdx.x;
    if (node >= n) return;
    float xi[FINP];
    #pragma unroll
    for (int k = 0; k < FINP; ++k) xi[k] = pre[(size_t)node * FINP + k];
    float s = SCALE ? dinv[node] : 1.f;
    float o[FOUT];
    #pragma unroll
    for (int fo = 0; fo < FOUT; ++fo) {
        float acc = sB[fo];
        #pragma unroll
        for (int k = 0; k < FINP; ++k) acc = fmaf(xi[k], sW[k * FOUT + fo], acc);
        if (RELU) acc = fmaxf(acc, 0.f);
        o[fo] = acc * s;
    }
    if constexpr (HALFOUT) {
        unsigned* outh = (unsigned*)outv;
        #pragma unroll
        for (int fo = 0; fo < FOUT / 2; ++fo)
            outh[(size_t)node * (FOUT / 2) + fo] = f2h(o[2 * fo], o[2 * fo + 1]);
    } else {
        float* outf = (float*)outv;
        #pragma unroll
        for (int fo = 0; fo < FOUT; ++fo) outf[(size_t)node * FOUT + fo] = o[fo];
    }
}

// ---------------- launch ----------------

extern "C" void kernel_launch(void* const* d_in, const int* in_sizes, int n_in,
                              void* d_out, int out_size, void* d_ws, size_t ws_size,
                              hipStream_t stream) {
    const float* x  = (const float*)d_in[0];
    const int*   ei = (const int*)d_in[1];
    const float* W1 = (const float*)d_in[2];
    const float* b1 = (const float*)d_in[3];
    const float* W2 = (const float*)d_in[4];
    const float* b2 = (const float*)d_in[5];
    const float* W3 = (const float*)d_in[6];
    const float* b3 = (const float*)d_in[7];
    float* out = (float*)d_out;

    const int n = in_sizes[0] / 11;   // 100000
    const int E = in_sizes[1] / 2;    // 3200000
    const int* src = ei;
    const int* dst = ei + E;

    const int nbkt = (n + NPB - 1) >> NPB_SHIFT;        // 782
    const int HBr  = (E + CHUNK - 1) / CHUNK;           // 782
    const size_t len = (size_t)nbkt * HBr;              // 611,524
    const int nb = (int)((len + 8191) / 8192);          // 75 (<=128)

    char* ws = (char*)d_ws;
    size_t off = 0;
    auto alloc = [&](size_t bytes) {
        void* p = ws + off;
        off = (off + bytes + 255) & ~(size_t)255;
        return p;
    };
    int*      offbuf    = (int*)     alloc(len * 4);
    int*      partial   = (int*)     alloc((size_t)128 * 4);
    int*      ebuf      = (int*)     alloc((size_t)E * 4);
    int*      csr_src   = (int*)     alloc((size_t)E * 4);
    int*      row_start = (int*)     alloc((size_t)(n + 1) * 4);
    float*    dinv      = (float*)   alloc((size_t)n * 4);
    unsigned* g0h       = (unsigned*)alloc((size_t)n * 16 * 2);   // fp16 tables
    unsigned* g1h       = (unsigned*)alloc((size_t)n * 16 * 2);
    unsigned* g2h       = (unsigned*)alloc((size_t)n * 32 * 2);
    float*    preS      = (float*)   alloc((size_t)n * 16 * 4);   // pre1 / pre2
    float*    preL      = (float*)   alloc((size_t)n * 32 * 4);   // pre3
    (void)ws_size;

    const int B = 256;
    int gn   = (n + B - 1) / B;
    int gagg = (n + 3) / 4;           // one wave per node

    // ---- atomic-free CSR build (+ fused dinv/row_start/pad_scale->fp16) ----
    hist_kernel<<<HBr, B, 0, stream>>>(dst, offbuf, E, HBr, nbkt);
    scan_block8_kernel<<<nb, 1024, 0, stream>>>(offbuf, partial, (int)len);
    scan_partials_kernel<<<1, 64, 0, stream>>>(partial, nb);
    scatter_kernel<<<HBr, B, 0, stream>>>(src, dst, offbuf, partial, ebuf, E, HBr, nbkt);
    bucket_build_kernel<<<nbkt, B, 0, stream>>>(ebuf, offbuf, partial, x, csr_src, row_start,
                                                dinv, g0h, E, HBr, nbkt, n);

    // layer 1: agg(16-wide fp16) -> linear 11->16, relu, scale -> fp16 table
    aggregate_kernel<16><<<gagg, B, 0, stream>>>((const uint2*)g0h, row_start, csr_src, dinv,
                                                 (float4*)preS, n);
    linear_kernel<16, 11, 16, true, true, true><<<gn, B, 0, stream>>>(preS, W1, b1, dinv, g1h, n);

    // layer 2: agg(16 fp16) -> linear 16->32, relu, scale -> fp16 table
    aggregate_kernel<16><<<gagg, B, 0, stream>>>((const uint2*)g1h, row_start, csr_src, dinv,
                                                 (float4*)preS, n);
    linear_kernel<16, 16, 32, true, true, true><<<gn, B, 0, stream>>>(preS, W2, b2, dinv, g2h, n);

    // layer 3: agg(32 fp16) -> linear 32->64, no relu, no scale, fp32 out
    aggregate_kernel<32><<<gagg, B, 0, stream>>>((const uint2*)g2h, row_start, csr_src, dinv,
                                                 (float4*)preL, n);
    linear_kernel<32, 32, 64, false, false, false><<<gn, B, 0, stream>>>(preL, W3, b3, dinv, out, n);
}

// Round 13
// 188.438 us; speedup vs baseline: 1.2893x; 1.0672x over previous
//
#include <hip/hip_runtime.h>
#include <hip/hip_fp16.h>

// ---- bucket-sort CSR parameters (n <= 131072, so src/dst fit in 17 bits) ----
#define NPB_SHIFT 7
#define NPB       128      // nodes per bucket
#define CHUNK     4096     // edges per hist/scatter block (16 per thread)
#define STAGE_CAP 8192     // bucket_build LDS staging (ints); avg bucket ~4092
#define NBKT_MAX  1024     // LDS bin cap (needs nbkt <= 1024)

union U2H { unsigned u; __half2 h; };

__device__ inline float2 h2f(unsigned u) {
    U2H c; c.u = u;
    return __half22float2(c.h);
}

__device__ inline unsigned f2h(float a, float b) {
    U2H c; c.h = __float22half2_rn(make_float2(a, b));
    return c.u;
}

// ---------------- pass 1: per-block LDS histogram of dst buckets ----------------

__global__ void hist_kernel(const int* __restrict__ dst, int* __restrict__ hist,
                            int E, int HBr, int nbkt) {
    __shared__ int bins[NBKT_MAX];
    int tid = threadIdx.x;
    for (int i = tid; i < nbkt; i += 256) bins[i] = 0;
    __syncthreads();
    int start = blockIdx.x * CHUNK;
    #pragma unroll
    for (int j = 0; j < 16; ++j) {
        int e = start + j * 256 + tid;
        if (e < E) atomicAdd(&bins[dst[e] >> NPB_SHIFT], 1);
    }
    __syncthreads();
    for (int i = tid; i < nbkt; i += 256)
        hist[(size_t)i * HBr + blockIdx.x] = bins[i];
}

// ---------------- 2-phase exclusive scan over hist matrix (in place) ----------------

__global__ void scan_block8_kernel(int* data, int* __restrict__ partial, int len) {
    __shared__ int wtot[16];
    int tid = threadIdx.x, lane = tid & 63, wid = tid >> 6;
    int base = blockIdx.x * 8192 + tid * 8;
    int v[8]; int s = 0;
    #pragma unroll
    for (int j = 0; j < 8; ++j) {
        int i = base + j;
        v[j] = (i < len) ? data[i] : 0;
        s += v[j];
    }
    int inc = s;
    #pragma unroll
    for (int o = 1; o < 64; o <<= 1) { int t = __shfl_up(inc, o); if (lane >= o) inc += t; }
    if (lane == 63) wtot[wid] = inc;
    __syncthreads();
    if (tid == 0) {
        int run = 0;
        #pragma unroll
        for (int w = 0; w < 16; ++w) { int t = wtot[w]; wtot[w] = run; run += t; }
        partial[blockIdx.x] = run;
    }
    __syncthreads();
    int excl = wtot[wid] + inc - s;
    #pragma unroll
    for (int j = 0; j < 8; ++j) {
        int i = base + j;
        if (i < len) data[i] = excl;
        excl += v[j];
    }
}

__global__ void scan_partials_kernel(int* partial, int nb) {
    int t = threadIdx.x;  // 64 threads; nb <= 128
    int i0 = 2 * t, i1 = 2 * t + 1;
    int v0 = (i0 < nb) ? partial[i0] : 0;
    int v1 = (i1 < nb) ? partial[i1] : 0;
    int s = v0 + v1;
    int inc = s;
    #pragma unroll
    for (int o = 1; o < 64; o <<= 1) { int u = __shfl_up(inc, o); if (t >= o) inc += u; }
    int excl = inc - s;
    if (i0 < nb) partial[i0] = excl;
    if (i1 < nb) partial[i1] = excl + v0;
}

// ---------------- pass 2: tile-sort scatter into bucket-ordered ebuf ----------------

__global__ void scatter_kernel(const int* __restrict__ src, const int* __restrict__ dst,
                               const int* __restrict__ offbuf, const int* __restrict__ partial,
                               int* __restrict__ ebuf, int E, int HBr, int nbkt) {
    __shared__ int gbase[NBKT_MAX];
    __shared__ int thist[NBKT_MAX];
    __shared__ int toff[NBKT_MAX + 1];
    __shared__ int stage[CHUNK];
    __shared__ unsigned short bstage[CHUNK];
    __shared__ int wtot4[4];
    int tid = threadIdx.x, lane = tid & 63, wid = tid >> 6;
    for (int i = tid; i < nbkt; i += 256) {
        size_t idx = (size_t)i * HBr + blockIdx.x;
        gbase[i] = offbuf[idx] + partial[(int)(idx >> 13)];
    }
    for (int i = tid; i < NBKT_MAX; i += 256) thist[i] = 0;
    __syncthreads();
    int start = blockIdx.x * CHUNK;
    int s_[16], d_[16], r_[16];
    #pragma unroll
    for (int j = 0; j < 16; ++j) {
        int e = start + j * 256 + tid;
        if (e < E) {
            s_[j] = src[e];
            d_[j] = dst[e];
            r_[j] = atomicAdd(&thist[d_[j] >> NPB_SHIFT], 1);
        } else {
            d_[j] = -1;
        }
    }
    __syncthreads();
    int a0 = thist[4 * tid], a1 = thist[4 * tid + 1],
        a2 = thist[4 * tid + 2], a3 = thist[4 * tid + 3];
    int ss = a0 + a1 + a2 + a3;
    int inc = ss;
    #pragma unroll
    for (int o = 1; o < 64; o <<= 1) { int t = __shfl_up(inc, o); if (lane >= o) inc += t; }
    if (lane == 63) wtot4[wid] = inc;
    __syncthreads();
    int wbase = 0;
    for (int w = 0; w < wid; ++w) wbase += wtot4[w];
    int excl = wbase + inc - ss;
    toff[4 * tid]     = excl;
    toff[4 * tid + 1] = excl + a0;
    toff[4 * tid + 2] = excl + a0 + a1;
    toff[4 * tid + 3] = excl + a0 + a1 + a2;
    if (tid == 255) toff[1024] = excl + ss;  // total valid
    __syncthreads();
    #pragma unroll
    for (int j = 0; j < 16; ++j) {
        if (d_[j] >= 0) {
            int b = d_[j] >> NPB_SHIFT;
            int q = toff[b] + r_[j];
            stage[q]  = ((d_[j] & (NPB - 1)) << 17) | s_[j];
            bstage[q] = (unsigned short)b;
        }
    }
    __syncthreads();
    int total = toff[1024];
    for (int j = tid; j < total; j += 256) {
        int b = bstage[j];
        ebuf[gbase[b] + (j - toff[b])] = stage[j];
    }
}

// ---------------- pass 3: per-bucket CSR build + row_start + dinv + fused pad_scale (fp16) --

__global__ void bucket_build_kernel(const int* __restrict__ ebuf, const int* __restrict__ offbuf,
                                    const int* __restrict__ partial, const float* __restrict__ x,
                                    int* __restrict__ csr_src, int* __restrict__ row_start,
                                    float* __restrict__ dinv, unsigned* __restrict__ g0h,
                                    int E, int HBr, int nbkt, int n) {
    __shared__ int cnt[NPB], cur[NPB];
    __shared__ float dnl[NPB];
    __shared__ int stage[STAGE_CAP];
    __shared__ int wtot2[2];
    int tid = threadIdx.x;
    int k = blockIdx.x;
    size_t ib = (size_t)k * HBr;
    int bb = offbuf[ib] + partial[(int)(ib >> 13)];
    int be;
    if (k + 1 < nbkt) {
        size_t ie = (size_t)(k + 1) * HBr;
        be = offbuf[ie] + partial[(int)(ie >> 13)];
    } else be = E;
    int bsize = be - bb;
    if (tid < NPB) cnt[tid] = 0;
    __syncthreads();

    constexpr int J = 20;                       // 20*256 = 5120 edge cap (avg 4092)
    int v[J], r[J];
    bool fast = (bsize <= J * 256) && (bsize <= STAGE_CAP);
    if (fast) {
        #pragma unroll
        for (int j = 0; j < J; ++j) {
            int e = bb + tid + j * 256;
            if (e < be) { v[j] = ebuf[e]; r[j] = atomicAdd(&cnt[v[j] >> 17], 1); }
            else v[j] = -1;
        }
    } else {
        for (int e = bb + tid; e < be; e += 256) atomicAdd(&cnt[ebuf[e] >> 17], 1);
    }
    __syncthreads();

    int lane = tid & 63, wid = tid >> 6;
    int c = 0, inc = 0;
    if (tid < NPB) {
        c = cnt[tid];
        inc = c;
        #pragma unroll
        for (int o = 1; o < 64; o <<= 1) { int t = __shfl_up(inc, o); if (lane >= o) inc += t; }
        if (lane == 63) wtot2[wid] = inc;
    }
    __syncthreads();
    if (tid < NPB) {
        int base = (wid == 1) ? wtot2[0] : 0;
        int excl = base + inc - c;
        cur[tid] = excl;
        int node = k * NPB + tid;
        if (node < n) {
            row_start[node] = bb + excl;
            float dn = rsqrtf((float)(c + 1));  // self-loop
            dinv[node] = dn;
            dnl[tid] = dn;
        }
    }
    if (k == 0 && tid == 0) row_start[n] = E;
    __syncthreads();

    // fused pad_scale into fp16: g0[node] = half(pad16(x[node]) * dinv[node])
    {
        int base_node = k * NPB;
        for (int i = tid; i < NPB * 8; i += 256) {
            int ln = i >> 3, kk = i & 7;
            int node = base_node + ln;
            if (node < n) {
                float dn = dnl[ln];
                int f0 = 2 * kk, f1 = f0 + 1;
                float a = (f0 < 11) ? x[(size_t)node * 11 + f0] * dn : 0.f;
                float b = (f1 < 11) ? x[(size_t)node * 11 + f1] * dn : 0.f;
                g0h[(size_t)node * 8 + kk] = f2h(a, b);
            }
        }
    }

    if (fast) {
        #pragma unroll
        for (int j = 0; j < J; ++j)
            if (v[j] >= 0) stage[cur[v[j] >> 17] + r[j]] = v[j] & 0x1FFFF;
        __syncthreads();
        for (int j = tid; j < bsize; j += 256) csr_src[bb + j] = stage[j];  // coalesced
    } else if (bsize <= STAGE_CAP) {
        for (int e = bb + tid; e < be; e += 256) {
            int vv = ebuf[e];
            int rr = atomicAdd(&cur[vv >> 17], 1);
            stage[rr] = vv & 0x1FFFF;
        }
        __syncthreads();
        for (int j = tid; j < bsize; j += 256) csr_src[bb + j] = stage[j];
    } else {
        for (int e = bb + tid; e < be; e += 256) {
            int vv = ebuf[e];
            int rr = atomicAdd(&cur[vv >> 17], 1);
            csr_src[bb + rr] = vv & 0x1FFFF;
        }
    }
}

// ---------------- gather-aggregate over fp16 tables: 2 nodes per wave ----------------
// pre[d] = dinv[d] * (sum_{s in N(d)} g[s] + g[d]);  g rows carry dinv[s], stored fp16.
// 32-lane sub-wave per node: LPR lanes/row (uint2 = 4 halves each), NGRP=32/LPR rows
// per instruction per sub-wave. Two independent chains per wave -> 2x requests in
// flight vs one-node-per-wave; per-node instruction count unchanged.

template <int LPR, int NB>
__device__ inline void gather_batch_h(const uint2* __restrict__ gv, const int* __restrict__ csr,
                                      int p, int end, int nrem, int q, int grp, float* acc) {
    constexpr int NGRP = 32 / LPR;
    int s[NB]; float m[NB];
    #pragma unroll
    for (int u = 0; u < NB; ++u) {
        int slot = u * NGRP + grp;
        s[u] = csr[min(p + slot, end - 1)];               // clamped, in-bounds
        m[u] = (slot < nrem) ? 1.f : 0.f;
    }
    uint2 v[NB];
    #pragma unroll
    for (int u = 0; u < NB; ++u) v[u] = gv[(size_t)s[u] * LPR + q];
    #pragma unroll
    for (int u = 0; u < NB; ++u) {
        float2 a = h2f(v[u].x), b = h2f(v[u].y);
        acc[0] = fmaf(m[u], a.x, acc[0]);
        acc[1] = fmaf(m[u], a.y, acc[1]);
        acc[2] = fmaf(m[u], b.x, acc[2]);
        acc[3] = fmaf(m[u], b.y, acc[3]);
    }
}

template <int FIN>
__global__ void aggregate_kernel(const uint2* __restrict__ gv,
                                 const int* __restrict__ row_start,
                                 const int* __restrict__ csr_src,
                                 const float* __restrict__ dinv,
                                 float4* __restrict__ pre, int n) {
    constexpr int LPR  = FIN / 4;   // lanes per row (4 or 8)
    constexpr int NGRP = 32 / LPR;  // rows per instruction per sub-wave (8 or 4)
    int lane  = threadIdx.x & 63;
    int wid   = threadIdx.x >> 6;
    int sub   = lane >> 5;          // sub-wave 0/1
    int slane = lane & 31;
    int node  = (blockIdx.x * (blockDim.x >> 6) + wid) * 2 + sub;
    if (node >= n) return;
    int q   = slane & (LPR - 1);
    int grp = slane / LPR;          // 0..NGRP-1
    int beg = row_start[node];
    int end = row_start[node + 1];
    float acc[4] = {0.f, 0.f, 0.f, 0.f};

    int p = beg;
    // unmasked full batches: 8 instructions = 8*NGRP rows per sub-wave
    for (; p + 8 * NGRP <= end; p += 8 * NGRP) {
        int s[8];
        #pragma unroll
        for (int u = 0; u < 8; ++u) s[u] = csr_src[p + u * NGRP + grp];
        uint2 v[8];
        #pragma unroll
        for (int u = 0; u < 8; ++u) v[u] = gv[(size_t)s[u] * LPR + q];
        #pragma unroll
        for (int u = 0; u < 8; ++u) {
            float2 a = h2f(v[u].x), b = h2f(v[u].y);
            acc[0] += a.x; acc[1] += a.y; acc[2] += b.x; acc[3] += b.y;
        }
    }
    // deg-adaptive masked tail
    int nrem = end - p;
    if (nrem > 0) {
        if (nrem <= NGRP)          gather_batch_h<LPR, 1>(gv, csr_src, p, end, nrem, q, grp, acc);
        else if (nrem <= 2 * NGRP) gather_batch_h<LPR, 2>(gv, csr_src, p, end, nrem, q, grp, acc);
        else if (nrem <= 4 * NGRP) gather_batch_h<LPR, 4>(gv, csr_src, p, end, nrem, q, grp, acc);
        else                       gather_batch_h<LPR, 8>(gv, csr_src, p, end, nrem, q, grp, acc);
    }

    // butterfly-reduce across row groups within the 32-lane sub-wave
    #pragma unroll
    for (int off = LPR; off < 32; off <<= 1)
        #pragma unroll
        for (int c = 0; c < 4; ++c) acc[c] += __shfl_xor(acc[c], off);

    // add self row, scale by dinv[d], vector store by lanes grp==0 of each sub-wave
    float dn = dinv[node];
    uint2 sv = gv[(size_t)node * LPR + q];
    float2 a = h2f(sv.x), b = h2f(sv.y);
    float4 o;
    o.x = dn * (acc[0] + a.x);
    o.y = dn * (acc[1] + a.y);
    o.z = dn * (acc[2] + b.x);
    o.w = dn * (acc[3] + b.y);
    if (grp == 0) pre[(size_t)node * LPR + q] = o;
}

// ---------------- post-agg linear (thread-per-node) ----------------
// out = [relu](pre @ W + b) [* dinv];  HALFOUT packs the result to fp16 pairs.

template <int FINP, int FINR, int FOUT, bool RELU, bool SCALE, bool HALFOUT>
__global__ void linear_kernel(const float* __restrict__ pre, const float* __restrict__ W,
                              const float* __restrict__ bias, const float* __restrict__ dinv,
                              void* __restrict__ outv, int n) {
    __shared__ float sW[FINP * FOUT];
    __shared__ float sB[FOUT];
    for (int i = threadIdx.x; i < FINP * FOUT; i += blockDim.x)
        sW[i] = (i < FINR * FOUT) ? W[i] : 0.f;
    for (int i = threadIdx.x; i < FOUT; i += blockDim.x) sB[i] = bias[i];
    __syncthreads();
    int node = blockIdx.x * blockDim.x + threadIdx.x;
    if (node >= n) return;
    float xi[FINP];
    #pragma unroll
    for (int k = 0; k < FINP; ++k) xi[k] = pre[(size_t)node * FINP + k];
    float s = SCALE ? dinv[node] : 1.f;
    float o[FOUT];
    #pragma unroll
    for (int fo = 0; fo < FOUT; ++fo) {
        float acc = sB[fo];
        #pragma unroll
        for (int k = 0; k < FINP; ++k) acc = fmaf(xi[k], sW[k * FOUT + fo], acc);
        if (RELU) acc = fmaxf(acc, 0.f);
        o[fo] = acc * s;
    }
    if constexpr (HALFOUT) {
        unsigned* outh = (unsigned*)outv;
        #pragma unroll
        for (int fo = 0; fo < FOUT / 2; ++fo)
            outh[(size_t)node * (FOUT / 2) + fo] = f2h(o[2 * fo], o[2 * fo + 1]);
    } else {
        float* outf = (float*)outv;
        #pragma unroll
        for (int fo = 0; fo < FOUT; ++fo) outf[(size_t)node * FOUT + fo] = o[fo];
    }
}

// ---------------- launch ----------------

extern "C" void kernel_launch(void* const* d_in, const int* in_sizes, int n_in,
                              void* d_out, int out_size, void* d_ws, size_t ws_size,
                              hipStream_t stream) {
    const float* x  = (const float*)d_in[0];
    const int*   ei = (const int*)d_in[1];
    const float* W1 = (const float*)d_in[2];
    const float* b1 = (const float*)d_in[3];
    const float* W2 = (const float*)d_in[4];
    const float* b2 = (const float*)d_in[5];
    const float* W3 = (const float*)d_in[6];
    const float* b3 = (const float*)d_in[7];
    float* out = (float*)d_out;

    const int n = in_sizes[0] / 11;   // 100000
    const int E = in_sizes[1] / 2;    // 3200000
    const int* src = ei;
    const int* dst = ei + E;

    const int nbkt = (n + NPB - 1) >> NPB_SHIFT;        // 782
    const int HBr  = (E + CHUNK - 1) / CHUNK;           // 782
    const size_t len = (size_t)nbkt * HBr;              // 611,524
    const int nb = (int)((len + 8191) / 8192);          // 75 (<=128)

    char* ws = (char*)d_ws;
    size_t off = 0;
    auto alloc = [&](size_t bytes) {
        void* p = ws + off;
        off = (off + bytes + 255) & ~(size_t)255;
        return p;
    };
    int*      offbuf    = (int*)     alloc(len * 4);
    int*      partial   = (int*)     alloc((size_t)128 * 4);
    int*      ebuf      = (int*)     alloc((size_t)E * 4);
    int*      csr_src   = (int*)     alloc((size_t)E * 4);
    int*      row_start = (int*)     alloc((size_t)(n + 1) * 4);
    float*    dinv      = (float*)   alloc((size_t)n * 4);
    unsigned* g0h       = (unsigned*)alloc((size_t)n * 16 * 2);   // fp16 tables
    unsigned* g1h       = (unsigned*)alloc((size_t)n * 16 * 2);
    unsigned* g2h       = (unsigned*)alloc((size_t)n * 32 * 2);
    float*    preS      = (float*)   alloc((size_t)n * 16 * 4);   // pre1 / pre2
    float*    preL      = (float*)   alloc((size_t)n * 32 * 4);   // pre3
    (void)ws_size;

    const int B = 256;
    int gn   = (n + B - 1) / B;
    int gagg = (n + 7) / 8;           // 4 waves/block x 2 nodes/wave

    // ---- atomic-free CSR build (+ fused dinv/row_start/pad_scale->fp16) ----
    hist_kernel<<<HBr, B, 0, stream>>>(dst, offbuf, E, HBr, nbkt);
    scan_block8_kernel<<<nb, 1024, 0, stream>>>(offbuf, partial, (int)len);
    scan_partials_kernel<<<1, 64, 0, stream>>>(partial, nb);
    scatter_kernel<<<HBr, B, 0, stream>>>(src, dst, offbuf, partial, ebuf, E, HBr, nbkt);
    bucket_build_kernel<<<nbkt, B, 0, stream>>>(ebuf, offbuf, partial, x, csr_src, row_start,
                                                dinv, g0h, E, HBr, nbkt, n);

    // layer 1: agg(16-wide fp16) -> linear 11->16, relu, scale -> fp16 table
    aggregate_kernel<16><<<gagg, B, 0, stream>>>((const uint2*)g0h, row_start, csr_src, dinv,
                                                 (float4*)preS, n);
    linear_kernel<16, 11, 16, true, true, true><<<gn, B, 0, stream>>>(preS, W1, b1, dinv, g1h, n);

    // layer 2: agg(16 fp16) -> linear 16->32, relu, scale -> fp16 table
    aggregate_kernel<16><<<gagg, B, 0, stream>>>((const uint2*)g1h, row_start, csr_src, dinv,
                                                 (float4*)preS, n);
    linear_kernel<16, 16, 32, true, true, true><<<gn, B, 0, stream>>>(preS, W2, b2, dinv, g2h, n);

    // layer 3: agg(32 fp16) -> linear 32->64, no relu, no scale, fp32 out
    aggregate_kernel<32><<<gagg, B, 0, stream>>>((const uint2*)g2h, row_start, csr_src, dinv,
                                                 (float4*)preL, n);
    linear_kernel<32, 32, 64, false, false, false><<<gn, B, 0, stream>>>(preL, W3, b3, dinv, out, n);
}

// Round 14
// 186.703 us; speedup vs baseline: 1.3013x; 1.0093x over previous
//
#include <hip/hip_runtime.h>
#include <hip/hip_fp16.h>

// ---- bucket-sort CSR parameters (n <= 131072, so src/dst fit in 17 bits) ----
#define NPB_SHIFT 7
#define NPB       128      // nodes per bucket
#define CHUNK     4096     // edges per hist/scatter block (16 per thread)
#define STAGE_CAP 8192     // bucket_build LDS staging (ints); avg bucket ~4092
#define NBKT_MAX  1024     // LDS bin cap (needs nbkt <= 1024)

union U2H { unsigned u; __half2 h; };

__device__ inline float2 h2f(unsigned u) {
    U2H c; c.u = u;
    return __half22float2(c.h);
}

__device__ inline unsigned f2h(float a, float b) {
    U2H c; c.h = __float22half2_rn(make_float2(a, b));
    return c.u;
}

// ---------------- pass 1: per-block LDS histogram of dst buckets ----------------

__global__ void hist_kernel(const int* __restrict__ dst, int* __restrict__ hist,
                            int E, int HBr, int nbkt) {
    __shared__ int bins[NBKT_MAX];
    int tid = threadIdx.x;
    for (int i = tid; i < nbkt; i += 256) bins[i] = 0;
    __syncthreads();
    int start = blockIdx.x * CHUNK;
    #pragma unroll
    for (int j = 0; j < 16; ++j) {
        int e = start + j * 256 + tid;
        if (e < E) atomicAdd(&bins[dst[e] >> NPB_SHIFT], 1);
    }
    __syncthreads();
    for (int i = tid; i < nbkt; i += 256)
        hist[(size_t)i * HBr + blockIdx.x] = bins[i];
}

// ---------------- 2-phase exclusive scan over hist matrix (in place) ----------------

__global__ void scan_block8_kernel(int* data, int* __restrict__ partial, int len) {
    __shared__ int wtot[16];
    int tid = threadIdx.x, lane = tid & 63, wid = tid >> 6;
    int base = blockIdx.x * 8192 + tid * 8;
    int v[8]; int s = 0;
    #pragma unroll
    for (int j = 0; j < 8; ++j) {
        int i = base + j;
        v[j] = (i < len) ? data[i] : 0;
        s += v[j];
    }
    int inc = s;
    #pragma unroll
    for (int o = 1; o < 64; o <<= 1) { int t = __shfl_up(inc, o); if (lane >= o) inc += t; }
    if (lane == 63) wtot[wid] = inc;
    __syncthreads();
    if (tid == 0) {
        int run = 0;
        #pragma unroll
        for (int w = 0; w < 16; ++w) { int t = wtot[w]; wtot[w] = run; run += t; }
        partial[blockIdx.x] = run;
    }
    __syncthreads();
    int excl = wtot[wid] + inc - s;
    #pragma unroll
    for (int j = 0; j < 8; ++j) {
        int i = base + j;
        if (i < len) data[i] = excl;
        excl += v[j];
    }
}

__global__ void scan_partials_kernel(int* partial, int nb) {
    int t = threadIdx.x;  // 64 threads; nb <= 128
    int i0 = 2 * t, i1 = 2 * t + 1;
    int v0 = (i0 < nb) ? partial[i0] : 0;
    int v1 = (i1 < nb) ? partial[i1] : 0;
    int s = v0 + v1;
    int inc = s;
    #pragma unroll
    for (int o = 1; o < 64; o <<= 1) { int u = __shfl_up(inc, o); if (t >= o) inc += u; }
    int excl = inc - s;
    if (i0 < nb) partial[i0] = excl;
    if (i1 < nb) partial[i1] = excl + v0;
}

// ---------------- pass 2: tile-sort scatter into bucket-ordered ebuf ----------------

__global__ void scatter_kernel(const int* __restrict__ src, const int* __restrict__ dst,
                               const int* __restrict__ offbuf, const int* __restrict__ partial,
                               int* __restrict__ ebuf, int E, int HBr, int nbkt) {
    __shared__ int gbase[NBKT_MAX];
    __shared__ int thist[NBKT_MAX];
    __shared__ int toff[NBKT_MAX + 1];
    __shared__ int stage[CHUNK];
    __shared__ unsigned short bstage[CHUNK];
    __shared__ int wtot4[4];
    int tid = threadIdx.x, lane = tid & 63, wid = tid >> 6;
    for (int i = tid; i < nbkt; i += 256) {
        size_t idx = (size_t)i * HBr + blockIdx.x;
        gbase[i] = offbuf[idx] + partial[(int)(idx >> 13)];
    }
    for (int i = tid; i < NBKT_MAX; i += 256) thist[i] = 0;
    __syncthreads();
    int start = blockIdx.x * CHUNK;
    int s_[16], d_[16], r_[16];
    #pragma unroll
    for (int j = 0; j < 16; ++j) {
        int e = start + j * 256 + tid;
        if (e < E) {
            s_[j] = src[e];
            d_[j] = dst[e];
            r_[j] = atomicAdd(&thist[d_[j] >> NPB_SHIFT], 1);
        } else {
            d_[j] = -1;
        }
    }
    __syncthreads();
    int a0 = thist[4 * tid], a1 = thist[4 * tid + 1],
        a2 = thist[4 * tid + 2], a3 = thist[4 * tid + 3];
    int ss = a0 + a1 + a2 + a3;
    int inc = ss;
    #pragma unroll
    for (int o = 1; o < 64; o <<= 1) { int t = __shfl_up(inc, o); if (lane >= o) inc += t; }
    if (lane == 63) wtot4[wid] = inc;
    __syncthreads();
    int wbase = 0;
    for (int w = 0; w < wid; ++w) wbase += wtot4[w];
    int excl = wbase + inc - ss;
    toff[4 * tid]     = excl;
    toff[4 * tid + 1] = excl + a0;
    toff[4 * tid + 2] = excl + a0 + a1;
    toff[4 * tid + 3] = excl + a0 + a1 + a2;
    if (tid == 255) toff[1024] = excl + ss;  // total valid
    __syncthreads();
    #pragma unroll
    for (int j = 0; j < 16; ++j) {
        if (d_[j] >= 0) {
            int b = d_[j] >> NPB_SHIFT;
            int q = toff[b] + r_[j];
            stage[q]  = ((d_[j] & (NPB - 1)) << 17) | s_[j];
            bstage[q] = (unsigned short)b;
        }
    }
    __syncthreads();
    int total = toff[1024];
    for (int j = tid; j < total; j += 256) {
        int b = bstage[j];
        ebuf[gbase[b] + (j - toff[b])] = stage[j];
    }
}

// ---------------- pass 3: per-bucket CSR build + row_start + dinv + fused pad_scale (fp16) --

__global__ void bucket_build_kernel(const int* __restrict__ ebuf, const int* __restrict__ offbuf,
                                    const int* __restrict__ partial, const float* __restrict__ x,
                                    int* __restrict__ csr_src, int* __restrict__ row_start,
                                    float* __restrict__ dinv, unsigned* __restrict__ g0h,
                                    int E, int HBr, int nbkt, int n) {
    __shared__ int cnt[NPB], cur[NPB];
    __shared__ float dnl[NPB];
    __shared__ int stage[STAGE_CAP];
    __shared__ int wtot2[2];
    int tid = threadIdx.x;
    int k = blockIdx.x;
    size_t ib = (size_t)k * HBr;
    int bb = offbuf[ib] + partial[(int)(ib >> 13)];
    int be;
    if (k + 1 < nbkt) {
        size_t ie = (size_t)(k + 1) * HBr;
        be = offbuf[ie] + partial[(int)(ie >> 13)];
    } else be = E;
    int bsize = be - bb;
    if (tid < NPB) cnt[tid] = 0;
    __syncthreads();

    constexpr int J = 20;                       // 20*256 = 5120 edge cap (avg 4092)
    int v[J], r[J];
    bool fast = (bsize <= J * 256) && (bsize <= STAGE_CAP);
    if (fast) {
        #pragma unroll
        for (int j = 0; j < J; ++j) {
            int e = bb + tid + j * 256;
            if (e < be) { v[j] = ebuf[e]; r[j] = atomicAdd(&cnt[v[j] >> 17], 1); }
            else v[j] = -1;
        }
    } else {
        for (int e = bb + tid; e < be; e += 256) atomicAdd(&cnt[ebuf[e] >> 17], 1);
    }
    __syncthreads();

    int lane = tid & 63, wid = tid >> 6;
    int c = 0, inc = 0;
    if (tid < NPB) {
        c = cnt[tid];
        inc = c;
        #pragma unroll
        for (int o = 1; o < 64; o <<= 1) { int t = __shfl_up(inc, o); if (lane >= o) inc += t; }
        if (lane == 63) wtot2[wid] = inc;
    }
    __syncthreads();
    if (tid < NPB) {
        int base = (wid == 1) ? wtot2[0] : 0;
        int excl = base + inc - c;
        cur[tid] = excl;
        int node = k * NPB + tid;
        if (node < n) {
            row_start[node] = bb + excl;
            float dn = rsqrtf((float)(c + 1));  // self-loop
            dinv[node] = dn;
            dnl[tid] = dn;
        }
    }
    if (k == 0 && tid == 0) row_start[n] = E;
    __syncthreads();

    // fused pad_scale into fp16: g0[node] = half(pad16(x[node]) * dinv[node])
    {
        int base_node = k * NPB;
        for (int i = tid; i < NPB * 8; i += 256) {
            int ln = i >> 3, kk = i & 7;
            int node = base_node + ln;
            if (node < n) {
                float dn = dnl[ln];
                int f0 = 2 * kk, f1 = f0 + 1;
                float a = (f0 < 11) ? x[(size_t)node * 11 + f0] * dn : 0.f;
                float b = (f1 < 11) ? x[(size_t)node * 11 + f1] * dn : 0.f;
                g0h[(size_t)node * 8 + kk] = f2h(a, b);
            }
        }
    }

    if (fast) {
        #pragma unroll
        for (int j = 0; j < J; ++j)
            if (v[j] >= 0) stage[cur[v[j] >> 17] + r[j]] = v[j] & 0x1FFFF;
        __syncthreads();
        for (int j = tid; j < bsize; j += 256) csr_src[bb + j] = stage[j];  // coalesced
    } else if (bsize <= STAGE_CAP) {
        for (int e = bb + tid; e < be; e += 256) {
            int vv = ebuf[e];
            int rr = atomicAdd(&cur[vv >> 17], 1);
            stage[rr] = vv & 0x1FFFF;
        }
        __syncthreads();
        for (int j = tid; j < bsize; j += 256) csr_src[bb + j] = stage[j];
    } else {
        for (int e = bb + tid; e < be; e += 256) {
            int vv = ebuf[e];
            int rr = atomicAdd(&cur[vv >> 17], 1);
            csr_src[bb + rr] = vv & 0x1FFFF;
        }
    }
}

// ---------------- gather-aggregate over fp16 tables: 4 nodes per wave ----------------
// pre[d] = dinv[d] * (sum_{s in N(d)} g[s] + g[d]);  g rows carry dinv[s], stored fp16.
// 16-lane sub-wave per node: LPR lanes/row (uint2 = 4 halves each), NGRP=16/LPR rows
// per instruction per sub-wave. Four independent chains per wave -> 4x requests in
// flight vs one-node-per-wave; per-node instruction count unchanged.

template <int LPR, int NB>
__device__ inline void gather_batch_h(const uint2* __restrict__ gv, const int* __restrict__ csr,
                                      int p, int end, int nrem, int q, int grp, float* acc) {
    constexpr int NGRP = 16 / LPR;
    int s[NB]; float m[NB];
    #pragma unroll
    for (int u = 0; u < NB; ++u) {
        int slot = u * NGRP + grp;
        s[u] = csr[min(p + slot, end - 1)];               // clamped, in-bounds
        m[u] = (slot < nrem) ? 1.f : 0.f;
    }
    uint2 v[NB];
    #pragma unroll
    for (int u = 0; u < NB; ++u) v[u] = gv[(size_t)s[u] * LPR + q];
    #pragma unroll
    for (int u = 0; u < NB; ++u) {
        float2 a = h2f(v[u].x), b = h2f(v[u].y);
        acc[0] = fmaf(m[u], a.x, acc[0]);
        acc[1] = fmaf(m[u], a.y, acc[1]);
        acc[2] = fmaf(m[u], b.x, acc[2]);
        acc[3] = fmaf(m[u], b.y, acc[3]);
    }
}

template <int FIN>
__global__ void aggregate_kernel(const uint2* __restrict__ gv,
                                 const int* __restrict__ row_start,
                                 const int* __restrict__ csr_src,
                                 const float* __restrict__ dinv,
                                 float4* __restrict__ pre, int n) {
    constexpr int LPR  = FIN / 4;   // lanes per row (4 or 8)
    constexpr int NGRP = 16 / LPR;  // rows per instruction per sub-wave (4 or 2)
    int lane  = threadIdx.x & 63;
    int wid   = threadIdx.x >> 6;
    int sub   = lane >> 4;          // sub-wave 0..3
    int slane = lane & 15;
    int node  = (blockIdx.x * (blockDim.x >> 6) + wid) * 4 + sub;
    if (node >= n) return;
    int q   = slane & (LPR - 1);
    int grp = slane / LPR;          // 0..NGRP-1
    int beg = row_start[node];
    int end = row_start[node + 1];
    float acc[4] = {0.f, 0.f, 0.f, 0.f};

    int p = beg;
    // unmasked full batches: 8 instructions = 8*NGRP rows per sub-wave
    for (; p + 8 * NGRP <= end; p += 8 * NGRP) {
        int s[8];
        #pragma unroll
        for (int u = 0; u < 8; ++u) s[u] = csr_src[p + u * NGRP + grp];
        uint2 v[8];
        #pragma unroll
        for (int u = 0; u < 8; ++u) v[u] = gv[(size_t)s[u] * LPR + q];
        #pragma unroll
        for (int u = 0; u < 8; ++u) {
            float2 a = h2f(v[u].x), b = h2f(v[u].y);
            acc[0] += a.x; acc[1] += a.y; acc[2] += b.x; acc[3] += b.y;
        }
    }
    // deg-adaptive masked tail
    int nrem = end - p;
    if (nrem > 0) {
        if (nrem <= NGRP)          gather_batch_h<LPR, 1>(gv, csr_src, p, end, nrem, q, grp, acc);
        else if (nrem <= 2 * NGRP) gather_batch_h<LPR, 2>(gv, csr_src, p, end, nrem, q, grp, acc);
        else if (nrem <= 4 * NGRP) gather_batch_h<LPR, 4>(gv, csr_src, p, end, nrem, q, grp, acc);
        else                       gather_batch_h<LPR, 8>(gv, csr_src, p, end, nrem, q, grp, acc);
    }

    // butterfly-reduce across row groups within the 16-lane sub-wave
    #pragma unroll
    for (int off = LPR; off < 16; off <<= 1)
        #pragma unroll
        for (int c = 0; c < 4; ++c) acc[c] += __shfl_xor(acc[c], off);

    // add self row, scale by dinv[d], vector store by lanes grp==0 of each sub-wave
    float dn = dinv[node];
    uint2 sv = gv[(size_t)node * LPR + q];
    float2 a = h2f(sv.x), b = h2f(sv.y);
    float4 o;
    o.x = dn * (acc[0] + a.x);
    o.y = dn * (acc[1] + a.y);
    o.z = dn * (acc[2] + b.x);
    o.w = dn * (acc[3] + b.y);
    if (grp == 0) pre[(size_t)node * LPR + q] = o;
}

// ---------------- post-agg linear (thread-per-node) ----------------
// out = [relu](pre @ W + b) [* dinv];  HALFOUT packs the result to fp16 pairs.

template <int FINP, int FINR, int FOUT, bool RELU, bool SCALE, bool HALFOUT>
__global__ void linear_kernel(const float* __restrict__ pre, const float* __restrict__ W,
                              const float* __restrict__ bias, const float* __restrict__ dinv,
                              void* __restrict__ outv, int n) {
    __shared__ float sW[FINP * FOUT];
    __shared__ float sB[FOUT];
    for (int i = threadIdx.x; i < FINP * FOUT; i += blockDim.x)
        sW[i] = (i < FINR * FOUT) ? W[i] : 0.f;
    for (int i = threadIdx.x; i < FOUT; i += blockDim.x) sB[i] = bias[i];
    __syncthreads();
    int node = blockIdx.x * blockDim.x + threadIdx.x;
    if (node >= n) return;
    float xi[FINP];
    #pragma unroll
    for (int k = 0; k < FINP; ++k) xi[k] = pre[(size_t)node * FINP + k];
    float s = SCALE ? dinv[node] : 1.f;
    float o[FOUT];
    #pragma unroll
    for (int fo = 0; fo < FOUT; ++fo) {
        float acc = sB[fo];
        #pragma unroll
        for (int k = 0; k < FINP; ++k) acc = fmaf(xi[k], sW[k * FOUT + fo], acc);
        if (RELU) acc = fmaxf(acc, 0.f);
        o[fo] = acc * s;
    }
    if constexpr (HALFOUT) {
        unsigned* outh = (unsigned*)outv;
        #pragma unroll
        for (int fo = 0; fo < FOUT / 2; ++fo)
            outh[(size_t)node * (FOUT / 2) + fo] = f2h(o[2 * fo], o[2 * fo + 1]);
    } else {
        float* outf = (float*)outv;
        #pragma unroll
        for (int fo = 0; fo < FOUT; ++fo) outf[(size_t)node * FOUT + fo] = o[fo];
    }
}

// ---------------- launch ----------------

extern "C" void kernel_launch(void* const* d_in, const int* in_sizes, int n_in,
                              void* d_out, int out_size, void* d_ws, size_t ws_size,
                              hipStream_t stream) {
    const float* x  = (const float*)d_in[0];
    const int*   ei = (const int*)d_in[1];
    const float* W1 = (const float*)d_in[2];
    const float* b1 = (const float*)d_in[3];
    const float* W2 = (const float*)d_in[4];
    const float* b2 = (const float*)d_in[5];
    const float* W3 = (const float*)d_in[6];
    const float* b3 = (const float*)d_in[7];
    float* out = (float*)d_out;

    const int n = in_sizes[0] / 11;   // 100000
    const int E = in_sizes[1] / 2;    // 3200000
    const int* src = ei;
    const int* dst = ei + E;

    const int nbkt = (n + NPB - 1) >> NPB_SHIFT;        // 782
    const int HBr  = (E + CHUNK - 1) / CHUNK;           // 782
    const size_t len = (size_t)nbkt * HBr;              // 611,524
    const int nb = (int)((len + 8191) / 8192);          // 75 (<=128)

    char* ws = (char*)d_ws;
    size_t off = 0;
    auto alloc = [&](size_t bytes) {
        void* p = ws + off;
        off = (off + bytes + 255) & ~(size_t)255;
        return p;
    };
    int*      offbuf    = (int*)     alloc(len * 4);
    int*      partial   = (int*)     alloc((size_t)128 * 4);
    int*      ebuf      = (int*)     alloc((size_t)E * 4);
    int*      csr_src   = (int*)     alloc((size_t)E * 4);
    int*      row_start = (int*)     alloc((size_t)(n + 1) * 4);
    float*    dinv      = (float*)   alloc((size_t)n * 4);
    unsigned* g0h       = (unsigned*)alloc((size_t)n * 16 * 2);   // fp16 tables
    unsigned* g1h       = (unsigned*)alloc((size_t)n * 16 * 2);
    unsigned* g2h       = (unsigned*)alloc((size_t)n * 32 * 2);
    float*    preS      = (float*)   alloc((size_t)n * 16 * 4);   // pre1 / pre2
    float*    preL      = (float*)   alloc((size_t)n * 32 * 4);   // pre3
    (void)ws_size;

    const int B = 256;
    int gn   = (n + B - 1) / B;
    int gagg = (n + 15) / 16;         // 4 waves/block x 4 nodes/wave

    // ---- atomic-free CSR build (+ fused dinv/row_start/pad_scale->fp16) ----
    hist_kernel<<<HBr, B, 0, stream>>>(dst, offbuf, E, HBr, nbkt);
    scan_block8_kernel<<<nb, 1024, 0, stream>>>(offbuf, partial, (int)len);
    scan_partials_kernel<<<1, 64, 0, stream>>>(partial, nb);
    scatter_kernel<<<HBr, B, 0, stream>>>(src, dst, offbuf, partial, ebuf, E, HBr, nbkt);
    bucket_build_kernel<<<nbkt, B, 0, stream>>>(ebuf, offbuf, partial, x, csr_src, row_start,
                                                dinv, g0h, E, HBr, nbkt, n);

    // layer 1: agg(16-wide fp16) -> linear 11->16, relu, scale -> fp16 table
    aggregate_kernel<16><<<gagg, B, 0, stream>>>((const uint2*)g0h, row_start, csr_src, dinv,
                                                 (float4*)preS, n);
    linear_kernel<16, 11, 16, true, true, true><<<gn, B, 0, stream>>>(preS, W1, b1, dinv, g1h, n);

    // layer 2: agg(16 fp16) -> linear 16->32, relu, scale -> fp16 table
    aggregate_kernel<16><<<gagg, B, 0, stream>>>((const uint2*)g1h, row_start, csr_src, dinv,
                                                 (float4*)preS, n);
    linear_kernel<16, 16, 32, true, true, true><<<gn, B, 0, stream>>>(preS, W2, b2, dinv, g2h, n);

    // layer 3: agg(32 fp16) -> linear 32->64, no relu, no scale, fp32 out
    aggregate_kernel<32><<<gagg, B, 0, stream>>>((const uint2*)g2h, row_start, csr_src, dinv,
                                                 (float4*)preL, n);
    linear_kernel<32, 32, 64, false, false, false><<<gn, B, 0, stream>>>(preL, W3, b3, dinv, out, n);
}

// Round 16
// 176.879 us; speedup vs baseline: 1.3736x; 1.0555x over previous
//
#include <hip/hip_runtime.h>
#include <hip/hip_fp16.h>

// ---- bucket-sort CSR parameters (n <= 131072, so src/dst fit in 17 bits) ----
#define NPB_SHIFT 7
#define NPB       128      // nodes per bucket
#define CHUNK     8192     // edges per hist/scatter block (16 per 512-thread)
#define STAGE_CAP 8192     // bucket_build LDS staging (ints); avg bucket ~4092
#define NBKT_MAX  1024     // LDS bin cap (needs nbkt <= 1024)

union U2H { unsigned u; __half2 h; };

__device__ inline float2 h2f(unsigned u) {
    U2H c; c.u = u;
    return __half22float2(c.h);
}

__device__ inline unsigned f2h(float a, float b) {
    U2H c; c.h = __float22half2_rn(make_float2(a, b));
    return c.u;
}

// ---------------- pass 1: per-block LDS histogram of dst buckets (512 threads) ----------------

__global__ void hist_kernel(const int* __restrict__ dst, int* __restrict__ hist,
                            int E, int HBr, int nbkt) {
    __shared__ int bins[NBKT_MAX];
    int tid = threadIdx.x;
    for (int i = tid; i < nbkt; i += 512) bins[i] = 0;
    __syncthreads();
    int start = blockIdx.x * CHUNK;
    #pragma unroll
    for (int j = 0; j < 16; ++j) {
        int e = start + j * 512 + tid;
        if (e < E) atomicAdd(&bins[dst[e] >> NPB_SHIFT], 1);
    }
    __syncthreads();
    for (int i = tid; i < nbkt; i += 512)
        hist[(size_t)i * HBr + blockIdx.x] = bins[i];
}

// ---------------- 2-phase exclusive scan over hist matrix (in place) ----------------

__global__ void scan_block8_kernel(int* data, int* __restrict__ partial, int len) {
    __shared__ int wtot[16];
    int tid = threadIdx.x, lane = tid & 63, wid = tid >> 6;
    int base = blockIdx.x * 8192 + tid * 8;
    int v[8]; int s = 0;
    #pragma unroll
    for (int j = 0; j < 8; ++j) {
        int i = base + j;
        v[j] = (i < len) ? data[i] : 0;
        s += v[j];
    }
    int inc = s;
    #pragma unroll
    for (int o = 1; o < 64; o <<= 1) { int t = __shfl_up(inc, o); if (lane >= o) inc += t; }
    if (lane == 63) wtot[wid] = inc;
    __syncthreads();
    if (tid == 0) {
        int run = 0;
        #pragma unroll
        for (int w = 0; w < 16; ++w) { int t = wtot[w]; wtot[w] = run; run += t; }
        partial[blockIdx.x] = run;
    }
    __syncthreads();
    int excl = wtot[wid] + inc - s;
    #pragma unroll
    for (int j = 0; j < 8; ++j) {
        int i = base + j;
        if (i < len) data[i] = excl;
        excl += v[j];
    }
}

__global__ void scan_partials_kernel(int* partial, int nb) {
    int t = threadIdx.x;  // 64 threads; nb <= 128
    int i0 = 2 * t, i1 = 2 * t + 1;
    int v0 = (i0 < nb) ? partial[i0] : 0;
    int v1 = (i1 < nb) ? partial[i1] : 0;
    int s = v0 + v1;
    int inc = s;
    #pragma unroll
    for (int o = 1; o < 64; o <<= 1) { int u = __shfl_up(inc, o); if (t >= o) inc += u; }
    int excl = inc - s;
    if (i0 < nb) partial[i0] = excl;
    if (i1 < nb) partial[i1] = excl + v0;
}

// ---------------- pass 2: tile-sort scatter into bucket-ordered ebuf (512 threads) ----------
// payload packed: (dst & 127) << 17 | src   (src < 2^17)
// global offsets = offbuf[..] + partial[idx>>13]  (base folded in here)

__global__ void scatter_kernel(const int* __restrict__ src, const int* __restrict__ dst,
                               const int* __restrict__ offbuf, const int* __restrict__ partial,
                               int* __restrict__ ebuf, int E, int HBr, int nbkt) {
    __shared__ int gbase[NBKT_MAX];
    __shared__ int thist[NBKT_MAX];
    __shared__ int toff[NBKT_MAX + 1];
    __shared__ int stage[CHUNK];
    __shared__ unsigned short bstage[CHUNK];
    __shared__ int wtot8[8];
    int tid = threadIdx.x, lane = tid & 63, wid = tid >> 6;
    for (int i = tid; i < nbkt; i += 512) {
        size_t idx = (size_t)i * HBr + blockIdx.x;
        gbase[i] = offbuf[idx] + partial[(int)(idx >> 13)];
    }
    for (int i = tid; i < NBKT_MAX; i += 512) thist[i] = 0;
    __syncthreads();
    int start = blockIdx.x * CHUNK;
    int s_[16], d_[16], r_[16];
    #pragma unroll
    for (int j = 0; j < 16; ++j) {
        int e = start + j * 512 + tid;
        if (e < E) {
            s_[j] = src[e];
            d_[j] = dst[e];
            r_[j] = atomicAdd(&thist[d_[j] >> NPB_SHIFT], 1);
        } else {
            d_[j] = -1;
        }
    }
    __syncthreads();
    // exclusive scan of thist[0..1023]: 512 threads x 2 bins
    int a0 = thist[2 * tid], a1 = thist[2 * tid + 1];
    int ss = a0 + a1;
    int inc = ss;
    #pragma unroll
    for (int o = 1; o < 64; o <<= 1) { int t = __shfl_up(inc, o); if (lane >= o) inc += t; }
    if (lane == 63) wtot8[wid] = inc;
    __syncthreads();
    int wbase = 0;
    for (int w = 0; w < wid; ++w) wbase += wtot8[w];
    int excl = wbase + inc - ss;
    toff[2 * tid]     = excl;
    toff[2 * tid + 1] = excl + a0;
    if (tid == 511) toff[1024] = excl + ss;  // total valid
    __syncthreads();
    #pragma unroll
    for (int j = 0; j < 16; ++j) {
        if (d_[j] >= 0) {
            int b = d_[j] >> NPB_SHIFT;
            int q = toff[b] + r_[j];
            stage[q]  = ((d_[j] & (NPB - 1)) << 17) | s_[j];
            bstage[q] = (unsigned short)b;
        }
    }
    __syncthreads();
    int total = toff[1024];
    for (int j = tid; j < total; j += 512) {
        int b = bstage[j];
        ebuf[gbase[b] + (j - toff[b])] = stage[j];
    }
}

// ---------------- pass 3: per-bucket CSR build + row_start + dinv + fused pad_scale (fp16) --

__global__ void bucket_build_kernel(const int* __restrict__ ebuf, const int* __restrict__ offbuf,
                                    const int* __restrict__ partial, const float* __restrict__ x,
                                    int* __restrict__ csr_src, int* __restrict__ row_start,
                                    float* __restrict__ dinv, unsigned* __restrict__ g0h,
                                    int E, int HBr, int nbkt, int n) {
    __shared__ int cnt[NPB], cur[NPB];
    __shared__ float dnl[NPB];
    __shared__ int stage[STAGE_CAP];
    __shared__ int wtot2[2];
    int tid = threadIdx.x;
    int k = blockIdx.x;
    size_t ib = (size_t)k * HBr;
    int bb = offbuf[ib] + partial[(int)(ib >> 13)];
    int be;
    if (k + 1 < nbkt) {
        size_t ie = (size_t)(k + 1) * HBr;
        be = offbuf[ie] + partial[(int)(ie >> 13)];
    } else be = E;
    int bsize = be - bb;
    if (tid < NPB) cnt[tid] = 0;
    __syncthreads();

    constexpr int J = 20;                       // 20*256 = 5120 edge cap (avg 4092)
    int v[J], r[J];
    bool fast = (bsize <= J * 256) && (bsize <= STAGE_CAP);
    if (fast) {
        #pragma unroll
        for (int j = 0; j < J; ++j) {
            int e = bb + tid + j * 256;
            if (e < be) { v[j] = ebuf[e]; r[j] = atomicAdd(&cnt[v[j] >> 17], 1); }
            else v[j] = -1;
        }
    } else {
        for (int e = bb + tid; e < be; e += 256) atomicAdd(&cnt[ebuf[e] >> 17], 1);
    }
    __syncthreads();

    int lane = tid & 63, wid = tid >> 6;
    int c = 0, inc = 0;
    if (tid < NPB) {
        c = cnt[tid];
        inc = c;
        #pragma unroll
        for (int o = 1; o < 64; o <<= 1) { int t = __shfl_up(inc, o); if (lane >= o) inc += t; }
        if (lane == 63) wtot2[wid] = inc;
    }
    __syncthreads();
    if (tid < NPB) {
        int base = (wid == 1) ? wtot2[0] : 0;
        int excl = base + inc - c;
        cur[tid] = excl;
        int node = k * NPB + tid;
        if (node < n) {
            row_start[node] = bb + excl;
            float dn = rsqrtf((float)(c + 1));  // self-loop
            dinv[node] = dn;
            dnl[tid] = dn;
        }
    }
    if (k == 0 && tid == 0) row_start[n] = E;
    __syncthreads();

    // fused pad_scale into fp16: g0[node] = half(pad16(x[node]) * dinv[node])
    {
        int base_node = k * NPB;
        for (int i = tid; i < NPB * 8; i += 256) {
            int ln = i >> 3, kk = i & 7;
            int node = base_node + ln;
            if (node < n) {
                float dn = dnl[ln];
                int f0 = 2 * kk, f1 = f0 + 1;
                float a = (f0 < 11) ? x[(size_t)node * 11 + f0] * dn : 0.f;
                float b = (f1 < 11) ? x[(size_t)node * 11 + f1] * dn : 0.f;
                g0h[(size_t)node * 8 + kk] = f2h(a, b);
            }
        }
    }

    if (fast) {
        #pragma unroll
        for (int j = 0; j < J; ++j)
            if (v[j] >= 0) stage[cur[v[j] >> 17] + r[j]] = v[j] & 0x1FFFF;
        __syncthreads();
        for (int j = tid; j < bsize; j += 256) csr_src[bb + j] = stage[j];  // coalesced
    } else if (bsize <= STAGE_CAP) {
        for (int e = bb + tid; e < be; e += 256) {
            int vv = ebuf[e];
            int rr = atomicAdd(&cur[vv >> 17], 1);
            stage[rr] = vv & 0x1FFFF;
        }
        __syncthreads();
        for (int j = tid; j < bsize; j += 256) csr_src[bb + j] = stage[j];
    } else {
        for (int e = bb + tid; e < be; e += 256) {
            int vv = ebuf[e];
            int rr = atomicAdd(&cur[vv >> 17], 1);
            csr_src[bb + rr] = vv & 0x1FFFF;
        }
    }
}

// ---------------- gather-aggregate over fp16 tables: 4 nodes per wave ----------------
// pre[d] = dinv[d] * (sum_{s in N(d)} g[s] + g[d]);  g rows carry dinv[s], stored fp16.
// 16-lane sub-wave per node: LPR lanes/row (uint2 = 4 halves each), NGRP=16/LPR rows
// per instruction per sub-wave. Four independent chains per wave.

template <int LPR, int NB>
__device__ inline void gather_batch_h(const uint2* __restrict__ gv, const int* __restrict__ csr,
                                      int p, int end, int nrem, int q, int grp, float* acc) {
    constexpr int NGRP = 16 / LPR;
    int s[NB]; float m[NB];
    #pragma unroll
    for (int u = 0; u < NB; ++u) {
        int slot = u * NGRP + grp;
        s[u] = csr[min(p + slot, end - 1)];               // clamped, in-bounds
        m[u] = (slot < nrem) ? 1.f : 0.f;
    }
    uint2 v[NB];
    #pragma unroll
    for (int u = 0; u < NB; ++u) v[u] = gv[(size_t)s[u] * LPR + q];
    #pragma unroll
    for (int u = 0; u < NB; ++u) {
        float2 a = h2f(v[u].x), b = h2f(v[u].y);
        acc[0] = fmaf(m[u], a.x, acc[0]);
        acc[1] = fmaf(m[u], a.y, acc[1]);
        acc[2] = fmaf(m[u], b.x, acc[2]);
        acc[3] = fmaf(m[u], b.y, acc[3]);
    }
}

template <int FIN>
__global__ void aggregate_kernel(const uint2* __restrict__ gv,
                                 const int* __restrict__ row_start,
                                 const int* __restrict__ csr_src,
                                 const float* __restrict__ dinv,
                                 float4* __restrict__ pre, int n) {
    constexpr int LPR  = FIN / 4;   // lanes per row (4 or 8)
    constexpr int NGRP = 16 / LPR;  // rows per instruction per sub-wave (4 or 2)
    int lane  = threadIdx.x & 63;
    int wid   = threadIdx.x >> 6;
    int sub   = lane >> 4;          // sub-wave 0..3
    int slane = lane & 15;
    int node  = (blockIdx.x * (blockDim.x >> 6) + wid) * 4 + sub;
    if (node >= n) return;
    int q   = slane & (LPR - 1);
    int grp = slane / LPR;          // 0..NGRP-1
    int beg = row_start[node];
    int end = row_start[node + 1];
    float acc[4] = {0.f, 0.f, 0.f, 0.f};

    int p = beg;
    // unmasked full batches: 8 instructions = 8*NGRP rows per sub-wave
    for (; p + 8 * NGRP <= end; p += 8 * NGRP) {
        int s[8];
        #pragma unroll
        for (int u = 0; u < 8; ++u) s[u] = csr_src[p + u * NGRP + grp];
        uint2 v[8];
        #pragma unroll
        for (int u = 0; u < 8; ++u) v[u] = gv[(size_t)s[u] * LPR + q];
        #pragma unroll
        for (int u = 0; u < 8; ++u) {
            float2 a = h2f(v[u].x), b = h2f(v[u].y);
            acc[0] += a.x; acc[1] += a.y; acc[2] += b.x; acc[3] += b.y;
        }
    }
    // deg-adaptive masked tail
    int nrem = end - p;
    if (nrem > 0) {
        if (nrem <= NGRP)          gather_batch_h<LPR, 1>(gv, csr_src, p, end, nrem, q, grp, acc);
        else if (nrem <= 2 * NGRP) gather_batch_h<LPR, 2>(gv, csr_src, p, end, nrem, q, grp, acc);
        else if (nrem <= 4 * NGRP) gather_batch_h<LPR, 4>(gv, csr_src, p, end, nrem, q, grp, acc);
        else                       gather_batch_h<LPR, 8>(gv, csr_src, p, end, nrem, q, grp, acc);
    }

    // butterfly-reduce across row groups within the 16-lane sub-wave
    #pragma unroll
    for (int off = LPR; off < 16; off <<= 1)
        #pragma unroll
        for (int c = 0; c < 4; ++c) acc[c] += __shfl_xor(acc[c], off);

    // add self row, scale by dinv[d], vector store by lanes grp==0 of each sub-wave
    float dn = dinv[node];
    uint2 sv = gv[(size_t)node * LPR + q];
    float2 a = h2f(sv.x), b = h2f(sv.y);
    float4 o;
    o.x = dn * (acc[0] + a.x);
    o.y = dn * (acc[1] + a.y);
    o.z = dn * (acc[2] + b.x);
    o.w = dn * (acc[3] + b.y);
    if (grp == 0) pre[(size_t)node * LPR + q] = o;
}

// ---------------- post-agg linear (thread-per-node) ----------------
// out = [relu](pre @ W + b) [* dinv];  HALFOUT packs the result to fp16 pairs.

template <int FINP, int FINR, int FOUT, bool RELU, bool SCALE, bool HALFOUT>
__global__ void linear_kernel(const float* __restrict__ pre, const float* __restrict__ W,
                              const float* __restrict__ bias, const float* __restrict__ dinv,
                              void* __restrict__ outv, int n) {
    __shared__ float sW[FINP * FOUT];
    __shared__ float sB[FOUT];
    for (int i = threadIdx.x; i < FINP * FOUT; i += blockDim.x)
        sW[i] = (i < FINR * FOUT) ? W[i] : 0.f;
    for (int i = threadIdx.x; i < FOUT; i += blockDim.x) sB[i] = bias[i];
    __syncthreads();
    int node = blockIdx.x * blockDim.x + threadIdx.x;
    if (node >= n) return;
    float xi[FINP];
    #pragma unroll
    for (int k = 0; k < FINP; ++k) xi[k] = pre[(size_t)node * FINP + k];
    float s = SCALE ? dinv[node] : 1.f;
    float o[FOUT];
    #pragma unroll
    for (int fo = 0; fo < FOUT; ++fo) {
        float acc = sB[fo];
        #pragma unroll
        for (int k = 0; k < FINP; ++k) acc = fmaf(xi[k], sW[k * FOUT + fo], acc);
        if (RELU) acc = fmaxf(acc, 0.f);
        o[fo] = acc * s;
    }
    if constexpr (HALFOUT) {
        unsigned* outh = (unsigned*)outv;
        #pragma unroll
        for (int fo = 0; fo < FOUT / 2; ++fo)
            outh[(size_t)node * (FOUT / 2) + fo] = f2h(o[2 * fo], o[2 * fo + 1]);
    } else {
        float* outf = (float*)outv;
        #pragma unroll
        for (int fo = 0; fo < FOUT; ++fo) outf[(size_t)node * FOUT + fo] = o[fo];
    }
}

// ---------------- launch ----------------

extern "C" void kernel_launch(void* const* d_in, const int* in_sizes, int n_in,
                              void* d_out, int out_size, void* d_ws, size_t ws_size,
                              hipStream_t stream) {
    const float* x  = (const float*)d_in[0];
    const int*   ei = (const int*)d_in[1];
    const float* W1 = (const float*)d_in[2];
    const float* b1 = (const float*)d_in[3];
    const float* W2 = (const float*)d_in[4];
    const float* b2 = (const float*)d_in[5];
    const float* W3 = (const float*)d_in[6];
    const float* b3 = (const float*)d_in[7];
    float* out = (float*)d_out;

    const int n = in_sizes[0] / 11;   // 100000
    const int E = in_sizes[1] / 2;    // 3200000
    const int* src = ei;
    const int* dst = ei + E;

    const int nbkt = (n + NPB - 1) >> NPB_SHIFT;        // 782
    const int HBr  = (E + CHUNK - 1) / CHUNK;           // 391
    const size_t len = (size_t)nbkt * HBr;              // 305,762
    const int nb = (int)((len + 8191) / 8192);          // 38 (<=128)

    char* ws = (char*)d_ws;
    size_t off = 0;
    auto alloc = [&](size_t bytes) {
        void* p = ws + off;
        off = (off + bytes + 255) & ~(size_t)255;
        return p;
    };
    int*      offbuf    = (int*)     alloc(len * 4);
    int*      partial   = (int*)     alloc((size_t)128 * 4);
    int*      ebuf      = (int*)     alloc((size_t)E * 4);
    int*      csr_src   = (int*)     alloc((size_t)E * 4);
    int*      row_start = (int*)     alloc((size_t)(n + 1) * 4);
    float*    dinv      = (float*)   alloc((size_t)n * 4);
    unsigned* g0h       = (unsigned*)alloc((size_t)n * 16 * 2);   // fp16 tables
    unsigned* g1h       = (unsigned*)alloc((size_t)n * 16 * 2);
    unsigned* g2h       = (unsigned*)alloc((size_t)n * 32 * 2);
    float*    preS      = (float*)   alloc((size_t)n * 16 * 4);   // pre1 / pre2
    float*    preL      = (float*)   alloc((size_t)n * 32 * 4);   // pre3
    (void)ws_size;

    const int B = 256;
    int gn   = (n + B - 1) / B;
    int gagg = (n + 15) / 16;         // 4 waves/block x 4 nodes/wave

    // ---- atomic-free CSR build (+ fused dinv/row_start/pad_scale->fp16) ----
    hist_kernel<<<HBr, 512, 0, stream>>>(dst, offbuf, E, HBr, nbkt);
    scan_block8_kernel<<<nb, 1024, 0, stream>>>(offbuf, partial, (int)len);
    scan_partials_kernel<<<1, 64, 0, stream>>>(partial, nb);
    scatter_kernel<<<HBr, 512, 0, stream>>>(src, dst, offbuf, partial, ebuf, E, HBr, nbkt);
    bucket_build_kernel<<<nbkt, 256, 0, stream>>>(ebuf, offbuf, partial, x, csr_src, row_start,
                                                  dinv, g0h, E, HBr, nbkt, n);

    // layer 1: agg(16-wide fp16) -> linear 11->16, relu, scale -> fp16 table
    aggregate_kernel<16><<<gagg, B, 0, stream>>>((const uint2*)g0h, row_start, csr_src, dinv,
                                                 (float4*)preS, n);
    linear_kernel<16, 11, 16, true, true, true><<<gn, B, 0, stream>>>(preS, W1, b1, dinv, g1h, n);

    // layer 2: agg(16 fp16) -> linear 16->32, relu, scale -> fp16 table
    aggregate_kernel<16><<<gagg, B, 0, stream>>>((const uint2*)g1h, row_start, csr_src, dinv,
                                                 (float4*)preS, n);
    linear_kernel<16, 16, 32, true, true, true><<<gn, B, 0, stream>>>(preS, W2, b2, dinv, g2h, n);

    // layer 3: agg(32 fp16) -> linear 32->64, no relu, no scale, fp32 out
    aggregate_kernel<32><<<gagg, B, 0, stream>>>((const uint2*)g2h, row_start, csr_src, dinv,
                                                 (float4*)preL, n);
    linear_kernel<32, 32, 64, false, false, false><<<gn, B, 0, stream>>>(preL, W3, b3, dinv, out, n);
}